// Round 12
// baseline (209.362 us; speedup 1.0000x reference)
//
#include <hip/hip_runtime.h>
#include <stdint.h>

typedef unsigned short u16;
typedef signed char i8;
typedef unsigned char u8;
typedef __attribute__((ext_vector_type(8))) short bf16x8;
typedef __attribute__((ext_vector_type(4))) float f32x4;
typedef __attribute__((ext_vector_type(4))) int i32x4;

#define S_LEN 1024
#define BATCH 4
#define EMB   1024
#define NH    16
#define DHEAD 64
#define BHEAD 64
#define NTOK  4096
#define KDIM  1024
#define NDIM  1024
#define EPSF  1e-8f
#define LOG2E 1.4426950408889634f

#define MFMAI8(a,b,c)  __builtin_amdgcn_mfma_i32_16x16x64_i8((a),(b),(c),0,0,0)

#define GLOAD16(g, l) __builtin_amdgcn_global_load_lds( \
    (const __attribute__((address_space(1))) void*)(g), \
    (__attribute__((address_space(3))) void*)(l), 16, 0, 0)

#define EXP2F(x) __builtin_amdgcn_exp2f(x)

__device__ __forceinline__ unsigned pack4(float a, float b, float c, float d){
  int qa = (int)a, qb = (int)b, qc = (int)c, qd = (int)d;
  return (unsigned)(qa & 255) | ((unsigned)(qb & 255) << 8) |
         ((unsigned)(qc & 255) << 16) | ((unsigned)(qd & 255) << 24);
}

__device__ __forceinline__ float wave_max(float v){
#pragma unroll
  for (int off = 32; off > 0; off >>= 1) v = fmaxf(v, __shfl_xor(v, off));
  return v;
}

// ---------------- scale slots ----------------
// 0 amax_query 1 amax_key 2 amax_value 3 amax_Wq 4 amax_Wk 5 amax_Wv 6 amax_Wo
// 7 amax_qproj 8 amax_kproj 9 amax_vproj 10 amax_attnout 11 unused 12 dummy 13 inv_l_max

// zero sc[0..15] and vtot[4096]
__global__ __launch_bounds__(256) void k_zero(float* sc, int* vtot){
  if (blockIdx.x == 0){
    if (threadIdx.x < 16) sc[threadIdx.x] = 0.0f;
  } else {
    vtot[(blockIdx.x - 1)*256 + threadIdx.x] = 0;
  }
}

struct AQDesc { const float* x; u8* y; int n4; int slot; float qdiv; float lo; };
struct AQTable { AQDesc d[7]; };

// merged absmax over 7 tensors; grid = 2048 (3x512 for q/k/v, 4x128 for weights)
__global__ __launch_bounds__(256) void k_absmax7(AQTable t, int* __restrict__ sci){
  const int bid = blockIdx.x;
  int seg, b0, nb;
  if (bid < 1536){ seg = bid >> 9; b0 = seg << 9; nb = 512; }
  else { seg = 3 + ((bid - 1536) >> 7); b0 = 1536 + ((seg - 3) << 7); nb = 128; }
  const AQDesc D = t.d[seg];
  float m = 0.0f;
  const float4* x4 = (const float4*)D.x;
  for (int i = (bid - b0)*256 + threadIdx.x; i < D.n4; i += nb*256){
    float4 v = x4[i];
    m = fmaxf(m, fmaxf(fmaxf(fabsf(v.x), fabsf(v.y)), fmaxf(fabsf(v.z), fabsf(v.w))));
  }
  m = wave_max(m);
  __shared__ float red[4];
  int lane = threadIdx.x & 63, w = threadIdx.x >> 6;
  if (lane == 0) red[w] = m;
  __syncthreads();
  if (threadIdx.x == 0){
    float mm = fmaxf(fmaxf(red[0], red[1]), fmaxf(red[2], red[3]));
    atomicMax(sci + D.slot, __float_as_int(mm));
  }
}

// merged fake-quant of 7 tensors to int8 grid
__global__ __launch_bounds__(256) void k_quant7(AQTable t, const float* __restrict__ sc){
  const int bid = blockIdx.x;
  int seg, b0, nb;
  if (bid < 1536){ seg = bid >> 9; b0 = seg << 9; nb = 512; }
  else { seg = 3 + ((bid - 1536) >> 7); b0 = 1536 + ((seg - 3) << 7); nb = 128; }
  const AQDesc D = t.d[seg];
  const float s = fmaxf(sc[D.slot] / D.qdiv, EPSF);
  const float lo = D.lo;
  const float4* x4 = (const float4*)D.x;
  unsigned* y4 = (unsigned*)D.y;
  for (int i = (bid - b0)*256 + threadIdx.x; i < D.n4; i += nb*256){
    float4 v = x4[i];
    float t0 = fminf(fmaxf(rintf(v.x / s), lo), 127.f);
    float t1 = fminf(fmaxf(rintf(v.y / s), lo), 127.f);
    float t2 = fminf(fmaxf(rintf(v.z / s), lo), 127.f);
    float t3 = fminf(fmaxf(rintf(v.w / s), lo), 127.f);
    y4[i] = pack4(t0, t1, t2, t3);
  }
}

// single-tensor quant to int8 (attention output)
__global__ __launch_bounds__(256) void k_quant(const float* __restrict__ x,
    u8* __restrict__ y, int n4, const float* __restrict__ sc, int slot){
  const float s = fmaxf(sc[slot] / 128.0f, EPSF);
  const float4* x4 = (const float4*)x;
  unsigned* y4 = (unsigned*)y;
  for (int i = blockIdx.x*256 + threadIdx.x; i < n4; i += gridDim.x*256){
    float4 v = x4[i];
    float t0 = fminf(fmaxf(rintf(v.x / s), -128.f), 127.f);
    float t1 = fminf(fmaxf(rintf(v.y / s), -128.f), 127.f);
    float t2 = fminf(fmaxf(rintf(v.z / s), -128.f), 127.f);
    float t3 = fminf(fmaxf(rintf(v.w / s), -128.f), 127.f);
    y4[i] = pack4(t0, t1, t2, t3);
  }
}

// ---------------- GEMM: 128x128 tile, BK=128 int8, 8 waves, 2-barrier + swizzle ----
__device__ __forceinline__ void gemm_body(const i8* __restrict__ A,
    const i8* __restrict__ W, const float* __restrict__ bias,
    float* __restrict__ out, float s_b, int rowBase, int colBase,
    int* __restrict__ amax_out, i8 (*As)[128], i8 (*Bs)[128], float* red){
  const int tid = threadIdx.x;
  const int wid = tid >> 6, lane = tid & 63;
  const int wm = wid >> 2, wn = wid & 3;
  const int rr = lane & 15, g = lane >> 4;
  const int srow = wid*8 + (lane >> 3);
  const int sco  = ((lane & 7) ^ (lane >> 3)) << 4;
  const i8* Arow0 = &A[(size_t)(rowBase + srow)*KDIM + sco];
  const i8* Arow1 = &A[(size_t)(rowBase + 64 + srow)*KDIM + sco];
  const i8* Wrow0 = &W[(size_t)(colBase + srow)*KDIM + sco];
  const i8* Wrow1 = &W[(size_t)(colBase + 64 + srow)*KDIM + sco];
  i32x4 c[4][2] = {};
  int aoff[4][2], boff[2][2];
#pragma unroll
  for (int i = 0; i < 4; i++){
    int row = wm*64 + i*16 + rr;
#pragma unroll
    for (int h = 0; h < 2; h++)
      aoff[i][h] = row*128 + (((h*4 + g) ^ (row & 7)) << 4);
  }
#pragma unroll
  for (int j = 0; j < 2; j++){
    int row = wn*32 + j*16 + rr;
#pragma unroll
    for (int h = 0; h < 2; h++)
      boff[j][h] = row*128 + (((h*4 + g) ^ (row & 7)) << 4);
  }
  for (int k0 = 0; k0 < KDIM; k0 += 128){
    __syncthreads();
    GLOAD16(Arow0 + k0, &As[wid*8][0]);
    GLOAD16(Arow1 + k0, &As[64 + wid*8][0]);
    GLOAD16(Wrow0 + k0, &Bs[wid*8][0]);
    GLOAD16(Wrow1 + k0, &Bs[64 + wid*8][0]);
    __syncthreads();
#pragma unroll
    for (int h = 0; h < 2; h++){
      i32x4 af[4], bfr[2];
#pragma unroll
      for (int i = 0; i < 4; i++) af[i]  = *(const i32x4*)((const i8*)As + aoff[i][h]);
#pragma unroll
      for (int j = 0; j < 2; j++) bfr[j] = *(const i32x4*)((const i8*)Bs + boff[j][h]);
#pragma unroll
      for (int i = 0; i < 4; i++)
#pragma unroll
        for (int j = 0; j < 2; j++)
          c[i][j] = MFMAI8(af[i], bfr[j], c[i][j]);
    }
  }
  float lmax = 0.0f;
  const int r0 = (lane >> 4) * 4, ccol = lane & 15;
#pragma unroll
  for (int j = 0; j < 2; j++){
    int col = colBase + wn*32 + j*16 + ccol;
    float rb = rintf(bias[col] / s_b);
#pragma unroll
    for (int i = 0; i < 4; i++){
      int rowb = rowBase + wm*64 + i*16 + r0;
#pragma unroll
      for (int rI = 0; rI < 4; rI++){
        float y = s_b * ((float)c[i][j][rI] + rb);
        out[(size_t)(rowb + rI)*NDIM + col] = y;
        lmax = fmaxf(lmax, fabsf(y));
      }
    }
  }
  lmax = wave_max(lmax);
  if (lane == 0) red[wid] = lmax;
  __syncthreads();
  if (tid == 0){
    float mm = red[0];
#pragma unroll
    for (int i2 = 1; i2 < 8; i2++) mm = fmaxf(mm, red[i2]);
    atomicMax(amax_out, __float_as_int(mm));
  }
}

// QKV projections fused: grid 768 (3 segs x 256 tiles), XCD-chunked swizzle
__global__ __launch_bounds__(512) void k_gemm3(const i8* __restrict__ Xall,
    const i8* __restrict__ Wall, const float* __restrict__ ball,
    float* __restrict__ Yall, const float* __restrict__ sc, int* __restrict__ sci){
  __shared__ i8 As[128][128];
  __shared__ i8 Bs[128][128];
  __shared__ float red[8];
  const int orig = blockIdx.x;
  const int xcd = orig & 7, sl = orig >> 3;
  const int seg = sl >> 5;
  const int t2 = xcd*32 + (sl & 31);
  const int by = t2 >> 3, bx = t2 & 7;
  const float s_x = fmaxf(sc[seg] / 128.0f, EPSF);
  const float s_w = fmaxf(sc[3 + seg] / 127.0f, EPSF);
  gemm_body(Xall + (size_t)seg*NTOK*KDIM, Wall + (size_t)seg*KDIM*NDIM,
            ball + seg*1024, Yall + (size_t)seg*NTOK*NDIM, s_x*s_w,
            by*128, bx*128, sci + 7 + seg, As, Bs, red);
}

// out-projection: grid 256
__global__ __launch_bounds__(512) void k_gemm1(const i8* __restrict__ A,
    const i8* __restrict__ W, const float* __restrict__ bias,
    float* __restrict__ out, const float* __restrict__ sc,
    int sx_slot, int sw_slot, int* __restrict__ amax_out){
  __shared__ i8 As[128][128];
  __shared__ i8 Bs[128][128];
  __shared__ float red[8];
  const int orig = blockIdx.x;
  const int t2 = (orig & 7)*32 + (orig >> 3);
  const int by = t2 >> 3, bx = t2 & 7;
  const float s_x = fmaxf(sc[sx_slot] / 128.0f, EPSF);
  const float s_w = fmaxf(sc[sw_slot] / 127.0f, EPSF);
  gemm_body(A, W, bias, out, s_x*s_w, by*128, bx*128, amax_out, As, Bs, red);
}

// q/k/v f32 (S,B,E) -> qh,kh int8 [BH][S][DH]; vt int8 [BH][DH][S]; vtot[bh][d] = sum_key v
__global__ __launch_bounds__(256) void k_quant_heads(const float* __restrict__ qf,
    const float* __restrict__ kf, const float* __restrict__ vf,
    i8* __restrict__ qh, i8* __restrict__ kh, i8* __restrict__ vt,
    int* __restrict__ vtot, const float* __restrict__ sc){
  const float s_q = fmaxf((sc[7]*0.125f)/128.0f, EPSF);  // scale of q/sqrt(64)
  const float s_k = fmaxf(sc[8]/128.0f, EPSF);
  const float s_v = fmaxf(sc[9]/128.0f, EPSF);
  __shared__ i8 tile[64][68];
  const int bx = blockIdx.x;
  const int st = bx & 15, hh = (bx >> 4) & 15, b = bx >> 8;
  const int t = threadIdx.x;
  const int sl = t >> 2, dc = (t & 3) * 16;
  const size_t row = (size_t)(st*64 + sl)*BATCH + b;
  const size_t ibase = row*EMB + hh*DHEAD + dc;
  const int bh = b*NH + hh;
  float vq[16], vk[16], vv[16];
#pragma unroll
  for (int i = 0; i < 4; i++){
    *(float4*)&vq[i*4] = *(const float4*)&qf[ibase + i*4];
    *(float4*)&vk[i*4] = *(const float4*)&kf[ibase + i*4];
    *(float4*)&vv[i*4] = *(const float4*)&vf[ibase + i*4];
  }
  alignas(16) i8 oq[16], ok[16];
#pragma unroll
  for (int i = 0; i < 16; i++){
    float tq = fminf(fmaxf(rintf((vq[i]*0.125f)/s_q), -128.f), 127.f);
    float tk = fminf(fmaxf(rintf(vk[i]/s_k), -128.f), 127.f);
    float tv = fminf(fmaxf(rintf(vv[i]/s_v), -128.f), 127.f);
    oq[i] = (i8)(int)tq; ok[i] = (i8)(int)tk;
    tile[dc + i][sl] = (i8)(int)tv;
  }
  const size_t qoff = ((size_t)bh*S_LEN + st*64 + sl)*DHEAD + dc;
  *(int4*)&qh[qoff] = *(const int4*)&oq[0];
  *(int4*)&kh[qoff] = *(const int4*)&ok[0];
  __syncthreads();
  const int d = t >> 2, sc4 = (t & 3) * 16;
  int ovi[4];
  int sum = 0;
#pragma unroll
  for (int w4 = 0; w4 < 4; w4++){
    unsigned x = *(const unsigned*)&tile[d][sc4 + w4*4];
    ovi[w4] = (int)x;
#pragma unroll
    for (int bb = 0; bb < 4; bb++) sum += (int)(i8)(x >> (8*bb));
  }
  const size_t voff = ((size_t)bh*DHEAD + d)*S_LEN + st*64 + sc4;
  *(int4*)&vt[voff] = *(const int4*)&ovi[0];
  sum += __shfl_xor(sum, 1);
  sum += __shfl_xor(sum, 2);
  if ((t & 3) == 0) atomicAdd(&vtot[bh*DHEAD + d], sum);
}

// attention pass 1: 2 waves / 32 q-rows per block, grid 2048. SWAPPED int8 QK^T,
// online (m,l) in log2 domain; per-lane scalars.
__global__ __launch_bounds__(128) void k_attn1(const i8* __restrict__ qh,
    const i8* __restrict__ kh, float* __restrict__ mrow, float* __restrict__ lrow,
    const float* __restrict__ sc, int* __restrict__ sci){
  __shared__ i8 Ks[64][64];
  __shared__ float red2[2];
  const int orig = blockIdx.x;
  const int tile = (orig & 7) * 256 + (orig >> 3);   // XCD-chunked swizzle (2048)
  const int bhead = tile >> 5, q0 = (tile & 31) * 32;
  const int tid = threadIdx.x, w = tid >> 6, lane = tid & 63;
  const int rr = lane & 15, g = lane >> 4;
  const float s_q = fmaxf((sc[7]*0.125f)/128.0f, EPSF);
  const float s_k = fmaxf(sc[8]/128.0f, EPSF);
  const float C1 = s_q * s_k * LOG2E;                // scores scaled to log2 domain
  const i8* qbase = qh + ((size_t)bhead*S_LEN + q0 + w*16)*DHEAD;
  const i8* kbase = kh + (size_t)bhead*S_LEN*DHEAD;
  i32x4 a = *(const i32x4*)&qbase[rr*DHEAD + g*16];  // Q fragment (B operand)
  // staging: wave w stages Ks rows 32w..32w+31 in 2 issues of 16 rows.
  // dest row = 32w+16j+(lane>>2), chunk = lane&3; source sel = (lane&3)^((row>>1)&3)
  // reduces to lane-only: (lane&3)^((lane>>3)&3).
  const int ssel = ((lane & 3) ^ ((lane >> 3) & 3)) << 4;
  const int sr0 = 32*w + (lane >> 2);
  const int sr1 = 32*w + 16 + (lane >> 2);
  float m = -1e30f, l = 0.0f;
  for (int cch = 0; cch < 16; cch++){
    const int n0 = cch * 64;
    __syncthreads();
    GLOAD16(&kbase[(size_t)(n0 + sr0)*DHEAD + ssel], &Ks[32*w][0]);
    GLOAD16(&kbase[(size_t)(n0 + sr1)*DHEAD + ssel], &Ks[32*w + 16][0]);
    __syncthreads();
    float sv[4][4];
#pragma unroll
    for (int nt = 0; nt < 4; nt++){
      int row = nt*16 + rr;
      i32x4 b = *(const i32x4*)((const i8*)Ks + row*64 + (((g ^ ((row >> 1) & 3))) << 4));
      i32x4 acc = {};
      acc = MFMAI8(b, a, acc);                       // SWAPPED: D[key][q]
#pragma unroll
      for (int r = 0; r < 4; r++) sv[nt][r] = (float)acc[r]*C1;
    }
    float cm = sv[0][0];
#pragma unroll
    for (int nt = 0; nt < 4; nt++)
#pragma unroll
      for (int r = 0; r < 4; r++) cm = fmaxf(cm, sv[nt][r]);
    float mn = fmaxf(m, cm);
    l *= EXP2F(m - mn);                              // 1.0 when max unchanged
    m = mn;
#pragma unroll
    for (int nt = 0; nt < 4; nt++)
#pragma unroll
      for (int r = 0; r < 4; r++) l += EXP2F(sv[nt][r] - m);
  }
  // merge (m,l) across the 4 g-lanes sharing q-row rr
#pragma unroll
  for (int off = 16; off < 64; off <<= 1){
    float mo = __shfl_xor(m, off), lo = __shfl_xor(l, off);
    float mn = fmaxf(m, mo);
    l = l*EXP2F(m - mn) + lo*EXP2F(mo - mn);
    m = mn;
  }
  if (g == 0){
    mrow[(size_t)bhead*S_LEN + q0 + w*16 + rr] = m;  // log2-domain max
    lrow[(size_t)bhead*S_LEN + q0 + w*16 + rr] = l;
  }
  float im = wave_max(1.0f / l);
  if (lane == 0) red2[w] = im;
  __syncthreads();
  if (tid == 0)
    atomicMax(sci + 13, __float_as_int(fmaxf(red2[0], red2[1])));
}

// attention pass 2: 2 waves / 32 q-rows per block, grid 2048. SWAPPED int8 QK^T +
// int8 PV with -128 offset; V swizzle fixed to (row>>1)&3 (2-way free).
__global__ __launch_bounds__(128) void k_attn2(const i8* __restrict__ qh,
    const i8* __restrict__ kh, const i8* __restrict__ vt,
    const float* __restrict__ mrow, const float* __restrict__ lrow,
    const int* __restrict__ vtot, float* __restrict__ aout,
    const float* __restrict__ sc, const int* __restrict__ sci,
    int* __restrict__ amax_out){
  __shared__ i8 Ks[64][64];
  __shared__ i8 Vs[64][64];
  __shared__ i8 P[2][16][68];       // stride 68 = 17 words: lanes spread banks
  __shared__ float red[2];
  const int orig = blockIdx.x;
  const int tile = (orig & 7) * 256 + (orig >> 3);   // XCD-chunked swizzle (2048)
  const int bhead = tile >> 5, q0 = (tile & 31) * 32;
  const int tid = threadIdx.x, w = tid >> 6, lane = tid & 63;
  const int rr = lane & 15, g = lane >> 4;
  const float s_q = fmaxf((sc[7]*0.125f)/128.0f, EPSF);
  const float s_k = fmaxf(sc[8]/128.0f, EPSF);
  const float C1 = s_q * s_k * LOG2E;
  const float s_v = fmaxf(sc[9]/128.0f, EPSF);
  const float s_a = fmaxf(__int_as_float(sci[13]) / 255.0f, EPSF);
  const float fac = s_a * s_v;
  const i8* qbase = qh + ((size_t)bhead*S_LEN + q0 + w*16)*DHEAD;
  const i8* kbase = kh + (size_t)bhead*S_LEN*DHEAD;
  const i8* vbase = vt + (size_t)bhead*DHEAD*S_LEN;
  i32x4 a = *(const i32x4*)&qbase[rr*DHEAD + g*16];  // Q fragment (B operand)
  // per-lane scalars for q-row rr: nb = log2(inv) - m  (inv folded into exponent)
  float nb;
  {
    size_t qr = (size_t)bhead*S_LEN + q0 + w*16 + rr;
    float inv = 1.0f / (lrow[qr] * s_a);
    nb = log2f(inv) - mrow[qr];
  }
  // staging maps (both K and V use (row>>1)&3 involution; lane-only source sel)
  const int ssel = ((lane & 3) ^ ((lane >> 3) & 3)) << 4;
  const int sr0 = 32*w + (lane >> 2);
  const int sr1 = 32*w + 16 + (lane >> 2);
  i32x4 cpv[4] = {};
  for (int cch = 0; cch < 16; cch++){
    const int n0 = cch * 64;
    __syncthreads();
    GLOAD16(&kbase[(size_t)(n0 + sr0)*DHEAD + ssel], &Ks[32*w][0]);
    GLOAD16(&kbase[(size_t)(n0 + sr1)*DHEAD + ssel], &Ks[32*w + 16][0]);
    GLOAD16(&vbase[(size_t)sr0*S_LEN + n0 + ssel], &Vs[32*w][0]);
    GLOAD16(&vbase[(size_t)sr1*S_LEN + n0 + ssel], &Vs[32*w + 16][0]);
    __syncthreads();
#pragma unroll
    for (int nt = 0; nt < 4; nt++){
      int row = nt*16 + rr;
      i32x4 b = *(const i32x4*)((const i8*)Ks + row*64 + (((g ^ ((row >> 1) & 3))) << 4));
      i32x4 acc = {};
      acc = MFMAI8(b, a, acc);                       // SWAPPED: D[key][q]
      unsigned pw = 0;
#pragma unroll
      for (int r = 0; r < 4; r++){
        float e  = EXP2F(fmaf((float)acc[r], C1, nb));
        int   pq = (int)fminf(rintf(e), 255.0f);
        pw |= (unsigned)pq << (8*r);
      }
      pw ^= 0x80808080u;                             // -128 per byte
      *(unsigned*)&P[w][rr][nt*16 + g*4] = pw;
    }
    // PV: within-wave P dependency (lgkmcnt orders write->read; no barrier needed)
    i32x4 pa;
    {
      const i8* pptr = &P[w][rr][g*16];
      pa[0] = *(const int*)(pptr + 0);
      pa[1] = *(const int*)(pptr + 4);
      pa[2] = *(const int*)(pptr + 8);
      pa[3] = *(const int*)(pptr + 12);
    }
#pragma unroll
    for (int f = 0; f < 4; f++){
      int row = f*16 + rr;
      i32x4 bv = *(const i32x4*)((const i8*)Vs + row*64 + (((g ^ ((row >> 1) & 3))) << 4));
      cpv[f] = MFMAI8(pa, bv, cpv[f]);
    }
  }
  const int b = bhead >> 4, hh = bhead & 15;
  float lmax = 0.0f;
#pragma unroll
  for (int f = 0; f < 4; f++){
    int d = f*16 + rr;
    int vcorr = 128 * vtot[bhead*DHEAD + d];
#pragma unroll
    for (int r = 0; r < 4; r++){
      int srow2 = q0 + w*16 + g*4 + r;
      float y = fac * (float)(cpv[f][r] + vcorr);
      aout[(size_t)(srow2*BATCH + b)*EMB + hh*DHEAD + d] = y;
      lmax = fmaxf(lmax, fabsf(y));
    }
  }
  lmax = wave_max(lmax);
  __syncthreads();
  if (lane == 0) red[w] = lmax;
  __syncthreads();
  if (tid == 0)
    atomicMax(amax_out, __float_as_int(fmaxf(red[0], red[1])));
}

extern "C" void kernel_launch(void* const* d_in, const int* in_sizes, int n_in,
                              void* d_out, int out_size, void* d_ws, size_t ws_size,
                              hipStream_t stream){
  const float* query = (const float*)d_in[0];
  const float* key   = (const float*)d_in[1];
  const float* value = (const float*)d_in[2];
  const float* inW   = (const float*)d_in[3];
  const float* inB   = (const float*)d_in[4];
  const float* outW  = (const float*)d_in[5];
  const float* outB  = (const float*)d_in[6];
  float* out = (float*)d_out;

  char* ws = (char*)d_ws;
  float* sc  = (float*)ws;
  int*   sci = (int*)ws;
  int*   vtotI = (int*)(ws + 256);               // 64x64 i32 = 16 KB
  u8* WQQ = (u8*)(ws + 256 + 16384);             // weights int8, 1MB each
  u8* WKQ = WQQ + 1024*1024;
  u8* WVQ = WKQ + 1024*1024;
  u8* WOQ = WVQ + 1024*1024;
  u8* XQ  = WOQ + 1024*1024;                     // acts int8, 4MB each
  u8* XK  = XQ + (size_t)NTOK*1024;
  u8* XV  = XK + (size_t)NTOK*1024;
  float* QF = (float*)(XV + (size_t)NTOK*1024);  // f32, 16MB each
  float* KF = QF + (size_t)NTOK*1024;
  float* VF = KF + (size_t)NTOK*1024;
  i8* VT = (i8*)(VF + (size_t)NTOK*1024);        // int8 V^T, 4MB
  float* MROW = (float*)(VT + (size_t)BHEAD*DHEAD*S_LEN);
  float* LROW = MROW + BHEAD*S_LEN;
  // reuse (lifetimes are disjoint along the serial stream):
  i8* QH  = (i8*)XQ;   i8* KH = (i8*)XK;         // proj-input quants dead after GEMMs
  float* AOUT = QF;                              // q f32 dead after k_quant_heads
  u8* AOQ = XV;                                  // v int8 input dead after gemm3

  AQTable tab;
  tab.d[0] = { query,             XQ,  NTOK*1024/4, 0, 128.f, -128.f };
  tab.d[1] = { key,               XK,  NTOK*1024/4, 1, 128.f, -128.f };
  tab.d[2] = { value,             XV,  NTOK*1024/4, 2, 128.f, -128.f };
  tab.d[3] = { inW,               WQQ, 1024*1024/4, 3, 127.f, -127.f };
  tab.d[4] = { inW + 1024*1024,   WKQ, 1024*1024/4, 4, 127.f, -127.f };
  tab.d[5] = { inW + 2*1024*1024, WVQ, 1024*1024/4, 5, 127.f, -127.f };
  tab.d[6] = { outW,              WOQ, 1024*1024/4, 6, 127.f, -127.f };

  k_zero<<<17, 256, 0, stream>>>(sc, vtotI);
  k_absmax7<<<2048, 256, 0, stream>>>(tab, sci);
  k_quant7<<<2048, 256, 0, stream>>>(tab, sc);
  k_gemm3<<<768, 512, 0, stream>>>((const i8*)XQ, (const i8*)WQQ, inB, QF, sc, sci);
  k_quant_heads<<<1024, 256, 0, stream>>>(QF, KF, VF, QH, KH, VT, vtotI, sc);
  k_attn1<<<2048, 128, 0, stream>>>(QH, KH, MROW, LROW, sc, sci);
  k_attn2<<<2048, 128, 0, stream>>>(QH, KH, VT, MROW, LROW, vtotI, AOUT, sc, sci, sci + 10);
  k_quant<<<1024, 256, 0, stream>>>(AOUT, AOQ, NTOK*1024/4, sc, 10);
  k_gemm1<<<256, 512, 0, stream>>>((const i8*)AOQ, (const i8*)WOQ, outB, out, sc, 10, 6, sci + 12);
}

// Round 13
// 186.432 us; speedup vs baseline: 1.1230x; 1.1230x over previous
//
#include <hip/hip_runtime.h>
#include <stdint.h>

typedef unsigned short u16;
typedef signed char i8;
typedef unsigned char u8;
typedef __attribute__((ext_vector_type(8))) short bf16x8;
typedef __attribute__((ext_vector_type(4))) float f32x4;
typedef __attribute__((ext_vector_type(4))) int i32x4;

#define S_LEN 1024
#define BATCH 4
#define EMB   1024
#define NH    16
#define DHEAD 64
#define BHEAD 64
#define NTOK  4096
#define KDIM  1024
#define NDIM  1024
#define EPSF  1e-8f
#define LOG2E 1.4426950408889634f

#define MFMAI8(a,b,c)  __builtin_amdgcn_mfma_i32_16x16x64_i8((a),(b),(c),0,0,0)

#define GLOAD16(g, l) __builtin_amdgcn_global_load_lds( \
    (const __attribute__((address_space(1))) void*)(g), \
    (__attribute__((address_space(3))) void*)(l), 16, 0, 0)

#define EXP2F(x) __builtin_amdgcn_exp2f(x)

__device__ __forceinline__ unsigned pack4(float a, float b, float c, float d){
  int qa = (int)a, qb = (int)b, qc = (int)c, qd = (int)d;
  return (unsigned)(qa & 255) | ((unsigned)(qb & 255) << 8) |
         ((unsigned)(qc & 255) << 16) | ((unsigned)(qd & 255) << 24);
}

__device__ __forceinline__ float wave_max(float v){
#pragma unroll
  for (int off = 32; off > 0; off >>= 1) v = fmaxf(v, __shfl_xor(v, off));
  return v;
}

// ---------------- scale slots ----------------
// 0 amax_query 1 amax_key 2 amax_value 3 amax_Wq 4 amax_Wk 5 amax_Wv 6 amax_Wo
// 7 amax_qproj 8 amax_kproj 9 amax_vproj 10 amax_attnout 11 unused 12 dummy 13 inv_l_max

// zero sc[0..15] and vtot[4096]
__global__ __launch_bounds__(256) void k_zero(float* sc, int* vtot){
  if (blockIdx.x == 0){
    if (threadIdx.x < 16) sc[threadIdx.x] = 0.0f;
  } else {
    vtot[(blockIdx.x - 1)*256 + threadIdx.x] = 0;
  }
}

struct AQDesc { const float* x; u8* y; int n4; int slot; float qdiv; float lo; };
struct AQTable { AQDesc d[7]; };

// merged absmax over 7 tensors; grid = 2048 (3x512 for q/k/v, 4x128 for weights)
__global__ __launch_bounds__(256) void k_absmax7(AQTable t, int* __restrict__ sci){
  const int bid = blockIdx.x;
  int seg, b0, nb;
  if (bid < 1536){ seg = bid >> 9; b0 = seg << 9; nb = 512; }
  else { seg = 3 + ((bid - 1536) >> 7); b0 = 1536 + ((seg - 3) << 7); nb = 128; }
  const AQDesc D = t.d[seg];
  float m = 0.0f;
  const float4* x4 = (const float4*)D.x;
  for (int i = (bid - b0)*256 + threadIdx.x; i < D.n4; i += nb*256){
    float4 v = x4[i];
    m = fmaxf(m, fmaxf(fmaxf(fabsf(v.x), fabsf(v.y)), fmaxf(fabsf(v.z), fabsf(v.w))));
  }
  m = wave_max(m);
  __shared__ float red[4];
  int lane = threadIdx.x & 63, w = threadIdx.x >> 6;
  if (lane == 0) red[w] = m;
  __syncthreads();
  if (threadIdx.x == 0){
    float mm = fmaxf(fmaxf(red[0], red[1]), fmaxf(red[2], red[3]));
    atomicMax(sci + D.slot, __float_as_int(mm));
  }
}

// merged fake-quant of 7 tensors to int8 grid
__global__ __launch_bounds__(256) void k_quant7(AQTable t, const float* __restrict__ sc){
  const int bid = blockIdx.x;
  int seg, b0, nb;
  if (bid < 1536){ seg = bid >> 9; b0 = seg << 9; nb = 512; }
  else { seg = 3 + ((bid - 1536) >> 7); b0 = 1536 + ((seg - 3) << 7); nb = 128; }
  const AQDesc D = t.d[seg];
  const float s = fmaxf(sc[D.slot] / D.qdiv, EPSF);
  const float lo = D.lo;
  const float4* x4 = (const float4*)D.x;
  unsigned* y4 = (unsigned*)D.y;
  for (int i = (bid - b0)*256 + threadIdx.x; i < D.n4; i += nb*256){
    float4 v = x4[i];
    float t0 = fminf(fmaxf(rintf(v.x / s), lo), 127.f);
    float t1 = fminf(fmaxf(rintf(v.y / s), lo), 127.f);
    float t2 = fminf(fmaxf(rintf(v.z / s), lo), 127.f);
    float t3 = fminf(fmaxf(rintf(v.w / s), lo), 127.f);
    y4[i] = pack4(t0, t1, t2, t3);
  }
}

// single-tensor quant to int8 (attention output)
__global__ __launch_bounds__(256) void k_quant(const float* __restrict__ x,
    u8* __restrict__ y, int n4, const float* __restrict__ sc, int slot){
  const float s = fmaxf(sc[slot] / 128.0f, EPSF);
  const float4* x4 = (const float4*)x;
  unsigned* y4 = (unsigned*)y;
  for (int i = blockIdx.x*256 + threadIdx.x; i < n4; i += gridDim.x*256){
    float4 v = x4[i];
    float t0 = fminf(fmaxf(rintf(v.x / s), -128.f), 127.f);
    float t1 = fminf(fmaxf(rintf(v.y / s), -128.f), 127.f);
    float t2 = fminf(fmaxf(rintf(v.z / s), -128.f), 127.f);
    float t3 = fminf(fmaxf(rintf(v.w / s), -128.f), 127.f);
    y4[i] = pack4(t0, t1, t2, t3);
  }
}

// ---------------- GEMM: 128x128 tile, BK=128 int8, 8 waves, 2-barrier + swizzle ----
__device__ __forceinline__ void gemm_body(const i8* __restrict__ A,
    const i8* __restrict__ W, const float* __restrict__ bias,
    float* __restrict__ out, float s_b, int rowBase, int colBase,
    int* __restrict__ amax_out, i8 (*As)[128], i8 (*Bs)[128], float* red){
  const int tid = threadIdx.x;
  const int wid = tid >> 6, lane = tid & 63;
  const int wm = wid >> 2, wn = wid & 3;
  const int rr = lane & 15, g = lane >> 4;
  const int srow = wid*8 + (lane >> 3);
  const int sco  = ((lane & 7) ^ (lane >> 3)) << 4;
  const i8* Arow0 = &A[(size_t)(rowBase + srow)*KDIM + sco];
  const i8* Arow1 = &A[(size_t)(rowBase + 64 + srow)*KDIM + sco];
  const i8* Wrow0 = &W[(size_t)(colBase + srow)*KDIM + sco];
  const i8* Wrow1 = &W[(size_t)(colBase + 64 + srow)*KDIM + sco];
  i32x4 c[4][2] = {};
  int aoff[4][2], boff[2][2];
#pragma unroll
  for (int i = 0; i < 4; i++){
    int row = wm*64 + i*16 + rr;
#pragma unroll
    for (int h = 0; h < 2; h++)
      aoff[i][h] = row*128 + (((h*4 + g) ^ (row & 7)) << 4);
  }
#pragma unroll
  for (int j = 0; j < 2; j++){
    int row = wn*32 + j*16 + rr;
#pragma unroll
    for (int h = 0; h < 2; h++)
      boff[j][h] = row*128 + (((h*4 + g) ^ (row & 7)) << 4);
  }
  for (int k0 = 0; k0 < KDIM; k0 += 128){
    __syncthreads();
    GLOAD16(Arow0 + k0, &As[wid*8][0]);
    GLOAD16(Arow1 + k0, &As[64 + wid*8][0]);
    GLOAD16(Wrow0 + k0, &Bs[wid*8][0]);
    GLOAD16(Wrow1 + k0, &Bs[64 + wid*8][0]);
    __syncthreads();
#pragma unroll
    for (int h = 0; h < 2; h++){
      i32x4 af[4], bfr[2];
#pragma unroll
      for (int i = 0; i < 4; i++) af[i]  = *(const i32x4*)((const i8*)As + aoff[i][h]);
#pragma unroll
      for (int j = 0; j < 2; j++) bfr[j] = *(const i32x4*)((const i8*)Bs + boff[j][h]);
#pragma unroll
      for (int i = 0; i < 4; i++)
#pragma unroll
        for (int j = 0; j < 2; j++)
          c[i][j] = MFMAI8(af[i], bfr[j], c[i][j]);
    }
  }
  float lmax = 0.0f;
  const int r0 = (lane >> 4) * 4, ccol = lane & 15;
#pragma unroll
  for (int j = 0; j < 2; j++){
    int col = colBase + wn*32 + j*16 + ccol;
    float rb = rintf(bias[col] / s_b);
#pragma unroll
    for (int i = 0; i < 4; i++){
      int rowb = rowBase + wm*64 + i*16 + r0;
#pragma unroll
      for (int rI = 0; rI < 4; rI++){
        float y = s_b * ((float)c[i][j][rI] + rb);
        out[(size_t)(rowb + rI)*NDIM + col] = y;
        lmax = fmaxf(lmax, fabsf(y));
      }
    }
  }
  lmax = wave_max(lmax);
  if (lane == 0) red[wid] = lmax;
  __syncthreads();
  if (tid == 0){
    float mm = red[0];
#pragma unroll
    for (int i2 = 1; i2 < 8; i2++) mm = fmaxf(mm, red[i2]);
    atomicMax(amax_out, __float_as_int(mm));
  }
}

// QKV projections fused: grid 768 (3 segs x 256 tiles), XCD-chunked swizzle
__global__ __launch_bounds__(512) void k_gemm3(const i8* __restrict__ Xall,
    const i8* __restrict__ Wall, const float* __restrict__ ball,
    float* __restrict__ Yall, const float* __restrict__ sc, int* __restrict__ sci){
  __shared__ i8 As[128][128];
  __shared__ i8 Bs[128][128];
  __shared__ float red[8];
  const int orig = blockIdx.x;
  const int xcd = orig & 7, sl = orig >> 3;
  const int seg = sl >> 5;
  const int t2 = xcd*32 + (sl & 31);
  const int by = t2 >> 3, bx = t2 & 7;
  const float s_x = fmaxf(sc[seg] / 128.0f, EPSF);
  const float s_w = fmaxf(sc[3 + seg] / 127.0f, EPSF);
  gemm_body(Xall + (size_t)seg*NTOK*KDIM, Wall + (size_t)seg*KDIM*NDIM,
            ball + seg*1024, Yall + (size_t)seg*NTOK*NDIM, s_x*s_w,
            by*128, bx*128, sci + 7 + seg, As, Bs, red);
}

// out-projection: grid 256
__global__ __launch_bounds__(512) void k_gemm1(const i8* __restrict__ A,
    const i8* __restrict__ W, const float* __restrict__ bias,
    float* __restrict__ out, const float* __restrict__ sc,
    int sx_slot, int sw_slot, int* __restrict__ amax_out){
  __shared__ i8 As[128][128];
  __shared__ i8 Bs[128][128];
  __shared__ float red[8];
  const int orig = blockIdx.x;
  const int t2 = (orig & 7)*32 + (orig >> 3);
  const int by = t2 >> 3, bx = t2 & 7;
  const float s_x = fmaxf(sc[sx_slot] / 128.0f, EPSF);
  const float s_w = fmaxf(sc[sw_slot] / 127.0f, EPSF);
  gemm_body(A, W, bias, out, s_x*s_w, by*128, bx*128, amax_out, As, Bs, red);
}

// q/k/v f32 (S,B,E) -> qh,kh int8 [BH][S][DH]; vt int8 [BH][DH][S]; vtot[bh][d] = sum_key v
__global__ __launch_bounds__(256) void k_quant_heads(const float* __restrict__ qf,
    const float* __restrict__ kf, const float* __restrict__ vf,
    i8* __restrict__ qh, i8* __restrict__ kh, i8* __restrict__ vt,
    int* __restrict__ vtot, const float* __restrict__ sc){
  const float s_q = fmaxf((sc[7]*0.125f)/128.0f, EPSF);  // scale of q/sqrt(64)
  const float s_k = fmaxf(sc[8]/128.0f, EPSF);
  const float s_v = fmaxf(sc[9]/128.0f, EPSF);
  __shared__ i8 tile[64][68];
  const int bx = blockIdx.x;
  const int st = bx & 15, hh = (bx >> 4) & 15, b = bx >> 8;
  const int t = threadIdx.x;
  const int sl = t >> 2, dc = (t & 3) * 16;
  const size_t row = (size_t)(st*64 + sl)*BATCH + b;
  const size_t ibase = row*EMB + hh*DHEAD + dc;
  const int bh = b*NH + hh;
  float vq[16], vk[16], vv[16];
#pragma unroll
  for (int i = 0; i < 4; i++){
    *(float4*)&vq[i*4] = *(const float4*)&qf[ibase + i*4];
    *(float4*)&vk[i*4] = *(const float4*)&kf[ibase + i*4];
    *(float4*)&vv[i*4] = *(const float4*)&vf[ibase + i*4];
  }
  alignas(16) i8 oq[16], ok[16];
#pragma unroll
  for (int i = 0; i < 16; i++){
    float tq = fminf(fmaxf(rintf((vq[i]*0.125f)/s_q), -128.f), 127.f);
    float tk = fminf(fmaxf(rintf(vk[i]/s_k), -128.f), 127.f);
    float tv = fminf(fmaxf(rintf(vv[i]/s_v), -128.f), 127.f);
    oq[i] = (i8)(int)tq; ok[i] = (i8)(int)tk;
    tile[dc + i][sl] = (i8)(int)tv;
  }
  const size_t qoff = ((size_t)bh*S_LEN + st*64 + sl)*DHEAD + dc;
  *(int4*)&qh[qoff] = *(const int4*)&oq[0];
  *(int4*)&kh[qoff] = *(const int4*)&ok[0];
  __syncthreads();
  const int d = t >> 2, sc4 = (t & 3) * 16;
  int ovi[4];
  int sum = 0;
#pragma unroll
  for (int w4 = 0; w4 < 4; w4++){
    unsigned x = *(const unsigned*)&tile[d][sc4 + w4*4];
    ovi[w4] = (int)x;
#pragma unroll
    for (int bb = 0; bb < 4; bb++) sum += (int)(i8)(x >> (8*bb));
  }
  const size_t voff = ((size_t)bh*DHEAD + d)*S_LEN + st*64 + sc4;
  *(int4*)&vt[voff] = *(const int4*)&ovi[0];
  sum += __shfl_xor(sum, 1);
  sum += __shfl_xor(sum, 2);
  if ((t & 3) == 0) atomicAdd(&vtot[bh*DHEAD + d], sum);
}

// attention pass 1: ONLINE softmax stats in log2 domain, SWAPPED int8 QK^T.
// 4 waves / 64 q-rows per block, grid 1024. Lane (rr,g) owns q-row rr.
__global__ __launch_bounds__(256) void k_attn1(const i8* __restrict__ qh,
    const i8* __restrict__ kh, float* __restrict__ mrow, float* __restrict__ lrow,
    const float* __restrict__ sc, int* __restrict__ sci){
  __shared__ i8 Ks[64][64];
  __shared__ float red2[4];
  const int orig = blockIdx.x;
  const int tile = (orig & 7) * 128 + (orig >> 3);   // XCD-chunked swizzle
  const int bhead = tile >> 4, q0 = (tile & 15) * 64;
  const int tid = threadIdx.x, w = tid >> 6, lane = tid & 63;
  const int rr = lane & 15, g = lane >> 4;
  const float s_q = fmaxf((sc[7]*0.125f)/128.0f, EPSF);
  const float s_k = fmaxf(sc[8]/128.0f, EPSF);
  const float C1 = s_q * s_k * LOG2E;                // scores scaled to log2 domain
  const i8* qbase = qh + ((size_t)bhead*S_LEN + q0 + w*16)*DHEAD;
  const i8* kbase = kh + (size_t)bhead*S_LEN*DHEAD;
  i32x4 a = *(const i32x4*)&qbase[rr*DHEAD + g*16];  // Q fragment (B operand)
  const int srow = w*16 + (lane >> 2);
  const int sco  = ((lane & 3) ^ ((srow >> 1) & 3)) << 4;
  float m = -1e30f, l = 0.0f;
  for (int cch = 0; cch < 16; cch++){
    const int n0 = cch * 64;
    __syncthreads();
    GLOAD16(&kbase[(size_t)(n0 + srow)*DHEAD + sco], &Ks[w*16][0]);
    __syncthreads();
    float sv[4][4];
#pragma unroll
    for (int nt = 0; nt < 4; nt++){
      int row = nt*16 + rr;
      i32x4 b = *(const i32x4*)((const i8*)Ks + row*64 + (((g ^ ((row >> 1) & 3))) << 4));
      i32x4 acc = {};
      acc = MFMAI8(b, a, acc);                       // SWAPPED: D[key][q]
#pragma unroll
      for (int r = 0; r < 4; r++) sv[nt][r] = (float)acc[r]*C1;
    }
    float cm = sv[0][0];
#pragma unroll
    for (int nt = 0; nt < 4; nt++)
#pragma unroll
      for (int r = 0; r < 4; r++) cm = fmaxf(cm, sv[nt][r]);
    float mn = fmaxf(m, cm);
    l *= EXP2F(m - mn);                              // 1.0 when max unchanged
    m = mn;
#pragma unroll
    for (int nt = 0; nt < 4; nt++)
#pragma unroll
      for (int r = 0; r < 4; r++) l += EXP2F(sv[nt][r] - m);
  }
  // merge (m,l) across the 4 g-lanes sharing q-row rr
#pragma unroll
  for (int off = 16; off < 64; off <<= 1){
    float mo = __shfl_xor(m, off), lo = __shfl_xor(l, off);
    float mn = fmaxf(m, mo);
    l = l*EXP2F(m - mn) + lo*EXP2F(mo - mn);
    m = mn;
  }
  if (g == 0){
    mrow[(size_t)bhead*S_LEN + q0 + w*16 + rr] = m;  // log2-domain max
    lrow[(size_t)bhead*S_LEN + q0 + w*16 + rr] = l;
  }
  float im = wave_max(1.0f / l);
  if (lane == 0) red2[w] = im;
  __syncthreads();
  if (tid == 0){
    float mm = fmaxf(fmaxf(red2[0], red2[1]), fmaxf(red2[2], red2[3]));
    atomicMax(sci + 13, __float_as_int(mm));
  }
}

// attention pass 2: SWAPPED int8 QK^T + int8 PV with -128 offset.
// 4 waves / 64 q-rows per block, grid 1024. V swizzle fixed to (row>>1)&3.
__global__ __launch_bounds__(256) void k_attn2(const i8* __restrict__ qh,
    const i8* __restrict__ kh, const i8* __restrict__ vt,
    const float* __restrict__ mrow, const float* __restrict__ lrow,
    const int* __restrict__ vtot, float* __restrict__ aout,
    const float* __restrict__ sc, const int* __restrict__ sci,
    int* __restrict__ amax_out){
  __shared__ i8 Ks[64][64];
  __shared__ i8 Vs[64][64];
  __shared__ i8 P[4][16][68];       // stride 68 = 17 words: lanes spread banks
  __shared__ float red[4];
  const int orig = blockIdx.x;
  const int tile = (orig & 7) * 128 + (orig >> 3);   // XCD-chunked swizzle
  const int bhead = tile >> 4, q0 = (tile & 15) * 64;
  const int tid = threadIdx.x, w = tid >> 6, lane = tid & 63;
  const int rr = lane & 15, g = lane >> 4;
  const float s_q = fmaxf((sc[7]*0.125f)/128.0f, EPSF);
  const float s_k = fmaxf(sc[8]/128.0f, EPSF);
  const float C1 = s_q * s_k * LOG2E;
  const float s_v = fmaxf(sc[9]/128.0f, EPSF);
  const float s_a = fmaxf(__int_as_float(sci[13]) / 255.0f, EPSF);
  const float fac = s_a * s_v;
  const i8* qbase = qh + ((size_t)bhead*S_LEN + q0 + w*16)*DHEAD;
  const i8* kbase = kh + (size_t)bhead*S_LEN*DHEAD;
  const i8* vbase = vt + (size_t)bhead*DHEAD*S_LEN;
  i32x4 a = *(const i32x4*)&qbase[rr*DHEAD + g*16];  // Q fragment (B operand)
  // per-lane scalars for q-row rr: nb = log2(inv) - m  (inv folded into exponent)
  float nb;
  {
    size_t qr = (size_t)bhead*S_LEN + q0 + w*16 + rr;
    float inv = 1.0f / (lrow[qr] * s_a);
    nb = log2f(inv) - mrow[qr];
  }
  const int srow = w*16 + (lane >> 2);
  // both K and V use the (row>>1)&3 involution; with srow = w*16+(lane>>2)
  // the source selector is lane-only: (lane&3) ^ ((lane>>3)&3)
  const int ssel = ((lane & 3) ^ ((lane >> 3) & 3)) << 4;
  i32x4 cpv[4] = {};
  for (int cch = 0; cch < 16; cch++){
    const int n0 = cch * 64;
    __syncthreads();
    GLOAD16(&kbase[(size_t)(n0 + srow)*DHEAD + ssel], &Ks[w*16][0]);
    GLOAD16(&vbase[(size_t)srow*S_LEN + n0 + ssel], &Vs[w*16][0]);
    __syncthreads();
#pragma unroll
    for (int nt = 0; nt < 4; nt++){
      int row = nt*16 + rr;
      i32x4 b = *(const i32x4*)((const i8*)Ks + row*64 + (((g ^ ((row >> 1) & 3))) << 4));
      i32x4 acc = {};
      acc = MFMAI8(b, a, acc);                       // SWAPPED: D[key][q]
      unsigned pw = 0;
#pragma unroll
      for (int r = 0; r < 4; r++){
        float e  = EXP2F(fmaf((float)acc[r], C1, nb));
        int   pq = (int)fminf(rintf(e), 255.0f);
        pw |= (unsigned)pq << (8*r);
      }
      pw ^= 0x80808080u;                             // -128 per byte
      *(unsigned*)&P[w][rr][nt*16 + g*4] = pw;
    }
    // PV: within-wave P dependency (lgkmcnt orders write->read; no barrier needed)
    i32x4 pa;
    {
      const i8* pptr = &P[w][rr][g*16];
      pa[0] = *(const int*)(pptr + 0);
      pa[1] = *(const int*)(pptr + 4);
      pa[2] = *(const int*)(pptr + 8);
      pa[3] = *(const int*)(pptr + 12);
    }
#pragma unroll
    for (int f = 0; f < 4; f++){
      int row = f*16 + rr;
      i32x4 bv = *(const i32x4*)((const i8*)Vs + row*64 + (((g ^ ((row >> 1) & 3))) << 4));
      cpv[f] = MFMAI8(pa, bv, cpv[f]);
    }
  }
  const int b = bhead >> 4, hh = bhead & 15;
  float lmax = 0.0f;
#pragma unroll
  for (int f = 0; f < 4; f++){
    int d = f*16 + rr;
    int vcorr = 128 * vtot[bhead*DHEAD + d];
#pragma unroll
    for (int r = 0; r < 4; r++){
      int srow2 = q0 + w*16 + g*4 + r;
      float y = fac * (float)(cpv[f][r] + vcorr);
      aout[(size_t)(srow2*BATCH + b)*EMB + hh*DHEAD + d] = y;
      lmax = fmaxf(lmax, fabsf(y));
    }
  }
  lmax = wave_max(lmax);
  __syncthreads();
  if (lane == 0) red[w] = lmax;
  __syncthreads();
  if (tid == 0){
    float mm = fmaxf(fmaxf(red[0], red[1]), fmaxf(red[2], red[3]));
    atomicMax(amax_out, __float_as_int(mm));
  }
}

extern "C" void kernel_launch(void* const* d_in, const int* in_sizes, int n_in,
                              void* d_out, int out_size, void* d_ws, size_t ws_size,
                              hipStream_t stream){
  const float* query = (const float*)d_in[0];
  const float* key   = (const float*)d_in[1];
  const float* value = (const float*)d_in[2];
  const float* inW   = (const float*)d_in[3];
  const float* inB   = (const float*)d_in[4];
  const float* outW  = (const float*)d_in[5];
  const float* outB  = (const float*)d_in[6];
  float* out = (float*)d_out;

  char* ws = (char*)d_ws;
  float* sc  = (float*)ws;
  int*   sci = (int*)ws;
  int*   vtotI = (int*)(ws + 256);               // 64x64 i32 = 16 KB
  u8* WQQ = (u8*)(ws + 256 + 16384);             // weights int8, 1MB each
  u8* WKQ = WQQ + 1024*1024;
  u8* WVQ = WKQ + 1024*1024;
  u8* WOQ = WVQ + 1024*1024;
  u8* XQ  = WOQ + 1024*1024;                     // acts int8, 4MB each
  u8* XK  = XQ + (size_t)NTOK*1024;
  u8* XV  = XK + (size_t)NTOK*1024;
  float* QF = (float*)(XV + (size_t)NTOK*1024);  // f32, 16MB each
  float* KF = QF + (size_t)NTOK*1024;
  float* VF = KF + (size_t)NTOK*1024;
  i8* VT = (i8*)(VF + (size_t)NTOK*1024);        // int8 V^T, 4MB
  float* MROW = (float*)(VT + (size_t)BHEAD*DHEAD*S_LEN);
  float* LROW = MROW + BHEAD*S_LEN;
  // reuse (lifetimes are disjoint along the serial stream):
  i8* QH  = (i8*)XQ;   i8* KH = (i8*)XK;         // proj-input quants dead after GEMMs
  float* AOUT = QF;                              // q f32 dead after k_quant_heads
  u8* AOQ = XV;                                  // v int8 input dead after gemm3

  AQTable tab;
  tab.d[0] = { query,             XQ,  NTOK*1024/4, 0, 128.f, -128.f };
  tab.d[1] = { key,               XK,  NTOK*1024/4, 1, 128.f, -128.f };
  tab.d[2] = { value,             XV,  NTOK*1024/4, 2, 128.f, -128.f };
  tab.d[3] = { inW,               WQQ, 1024*1024/4, 3, 127.f, -127.f };
  tab.d[4] = { inW + 1024*1024,   WKQ, 1024*1024/4, 4, 127.f, -127.f };
  tab.d[5] = { inW + 2*1024*1024, WVQ, 1024*1024/4, 5, 127.f, -127.f };
  tab.d[6] = { outW,              WOQ, 1024*1024/4, 6, 127.f, -127.f };

  k_zero<<<17, 256, 0, stream>>>(sc, vtotI);
  k_absmax7<<<2048, 256, 0, stream>>>(tab, sci);
  k_quant7<<<2048, 256, 0, stream>>>(tab, sc);
  k_gemm3<<<768, 512, 0, stream>>>((const i8*)XQ, (const i8*)WQQ, inB, QF, sc, sci);
  k_quant_heads<<<1024, 256, 0, stream>>>(QF, KF, VF, QH, KH, VT, vtotI, sc);
  k_attn1<<<1024, 256, 0, stream>>>(QH, KH, MROW, LROW, sc, sci);
  k_attn2<<<1024, 256, 0, stream>>>(QH, KH, VT, MROW, LROW, vtotI, AOUT, sc, sci, sci + 10);
  k_quant<<<1024, 256, 0, stream>>>(AOUT, AOQ, NTOK*1024/4, sc, 10);
  k_gemm1<<<256, 512, 0, stream>>>((const i8*)AOQ, (const i8*)WOQ, outB, out, sc, 10, 6, sci + 12);
}

// Round 14
// 182.090 us; speedup vs baseline: 1.1498x; 1.0238x over previous
//
#include <hip/hip_runtime.h>
#include <stdint.h>

typedef unsigned short u16;
typedef signed char i8;
typedef unsigned char u8;
typedef __attribute__((ext_vector_type(8))) short bf16x8;
typedef __attribute__((ext_vector_type(4))) float f32x4;
typedef __attribute__((ext_vector_type(4))) int i32x4;

#define S_LEN 1024
#define BATCH 4
#define EMB   1024
#define NH    16
#define DHEAD 64
#define BHEAD 64
#define NTOK  4096
#define KDIM  1024
#define NDIM  1024
#define EPSF  1e-8f
#define LOG2E 1.4426950408889634f

#define MFMAI8(a,b,c)  __builtin_amdgcn_mfma_i32_16x16x64_i8((a),(b),(c),0,0,0)

#define GLOAD16(g, l) __builtin_amdgcn_global_load_lds( \
    (const __attribute__((address_space(1))) void*)(g), \
    (__attribute__((address_space(3))) void*)(l), 16, 0, 0)

#define EXP2F(x) __builtin_amdgcn_exp2f(x)

__device__ __forceinline__ unsigned pack4(float a, float b, float c, float d){
  int qa = (int)a, qb = (int)b, qc = (int)c, qd = (int)d;
  return (unsigned)(qa & 255) | ((unsigned)(qb & 255) << 8) |
         ((unsigned)(qc & 255) << 16) | ((unsigned)(qd & 255) << 24);
}

__device__ __forceinline__ float wave_max(float v){
#pragma unroll
  for (int off = 32; off > 0; off >>= 1) v = fmaxf(v, __shfl_xor(v, off));
  return v;
}

// ---------------- scale slots ----------------
// 0 amax_query 1 amax_key 2 amax_value 3 amax_Wq 4 amax_Wk 5 amax_Wv 6 amax_Wo
// 7 amax_qproj 8 amax_kproj 9 amax_vproj 10 amax_attnout 11 unused 12 dummy 13 inv_l_max

// zero sc[0..15] and vtot[4096]
__global__ __launch_bounds__(256) void k_zero(float* sc, int* vtot){
  if (blockIdx.x == 0){
    if (threadIdx.x < 16) sc[threadIdx.x] = 0.0f;
  } else {
    vtot[(blockIdx.x - 1)*256 + threadIdx.x] = 0;
  }
}

struct AQDesc { const float* x; u8* y; int n4; int slot; float qdiv; float lo; };
struct AQTable { AQDesc d[7]; };

// merged absmax over 7 tensors; grid = 2048 (3x512 for q/k/v, 4x128 for weights)
__global__ __launch_bounds__(256) void k_absmax7(AQTable t, int* __restrict__ sci){
  const int bid = blockIdx.x;
  int seg, b0, nb;
  if (bid < 1536){ seg = bid >> 9; b0 = seg << 9; nb = 512; }
  else { seg = 3 + ((bid - 1536) >> 7); b0 = 1536 + ((seg - 3) << 7); nb = 128; }
  const AQDesc D = t.d[seg];
  float m = 0.0f;
  const float4* x4 = (const float4*)D.x;
  for (int i = (bid - b0)*256 + threadIdx.x; i < D.n4; i += nb*256){
    float4 v = x4[i];
    m = fmaxf(m, fmaxf(fmaxf(fabsf(v.x), fabsf(v.y)), fmaxf(fabsf(v.z), fabsf(v.w))));
  }
  m = wave_max(m);
  __shared__ float red[4];
  int lane = threadIdx.x & 63, w = threadIdx.x >> 6;
  if (lane == 0) red[w] = m;
  __syncthreads();
  if (threadIdx.x == 0){
    float mm = fmaxf(fmaxf(red[0], red[1]), fmaxf(red[2], red[3]));
    atomicMax(sci + D.slot, __float_as_int(mm));
  }
}

// merged fake-quant of 7 tensors to int8 grid
__global__ __launch_bounds__(256) void k_quant7(AQTable t, const float* __restrict__ sc){
  const int bid = blockIdx.x;
  int seg, b0, nb;
  if (bid < 1536){ seg = bid >> 9; b0 = seg << 9; nb = 512; }
  else { seg = 3 + ((bid - 1536) >> 7); b0 = 1536 + ((seg - 3) << 7); nb = 128; }
  const AQDesc D = t.d[seg];
  const float s = fmaxf(sc[D.slot] / D.qdiv, EPSF);
  const float lo = D.lo;
  const float4* x4 = (const float4*)D.x;
  unsigned* y4 = (unsigned*)D.y;
  for (int i = (bid - b0)*256 + threadIdx.x; i < D.n4; i += nb*256){
    float4 v = x4[i];
    float t0 = fminf(fmaxf(rintf(v.x / s), lo), 127.f);
    float t1 = fminf(fmaxf(rintf(v.y / s), lo), 127.f);
    float t2 = fminf(fmaxf(rintf(v.z / s), lo), 127.f);
    float t3 = fminf(fmaxf(rintf(v.w / s), lo), 127.f);
    y4[i] = pack4(t0, t1, t2, t3);
  }
}

// single-tensor quant to int8 (attention output)
__global__ __launch_bounds__(256) void k_quant(const float* __restrict__ x,
    u8* __restrict__ y, int n4, const float* __restrict__ sc, int slot){
  const float s = fmaxf(sc[slot] / 128.0f, EPSF);
  const float4* x4 = (const float4*)x;
  unsigned* y4 = (unsigned*)y;
  for (int i = blockIdx.x*256 + threadIdx.x; i < n4; i += gridDim.x*256){
    float4 v = x4[i];
    float t0 = fminf(fmaxf(rintf(v.x / s), -128.f), 127.f);
    float t1 = fminf(fmaxf(rintf(v.y / s), -128.f), 127.f);
    float t2 = fminf(fmaxf(rintf(v.z / s), -128.f), 127.f);
    float t3 = fminf(fmaxf(rintf(v.w / s), -128.f), 127.f);
    y4[i] = pack4(t0, t1, t2, t3);
  }
}

// ---------------- GEMM: 128x128 tile, BK=128 int8, 8 waves, 2-barrier + swizzle ----
__device__ __forceinline__ void gemm_body(const i8* __restrict__ A,
    const i8* __restrict__ W, const float* __restrict__ bias,
    float* __restrict__ out, float s_b, int rowBase, int colBase,
    int* __restrict__ amax_out, i8 (*As)[128], i8 (*Bs)[128], float* red){
  const int tid = threadIdx.x;
  const int wid = tid >> 6, lane = tid & 63;
  const int wm = wid >> 2, wn = wid & 3;
  const int rr = lane & 15, g = lane >> 4;
  const int srow = wid*8 + (lane >> 3);
  const int sco  = ((lane & 7) ^ (lane >> 3)) << 4;
  const i8* Arow0 = &A[(size_t)(rowBase + srow)*KDIM + sco];
  const i8* Arow1 = &A[(size_t)(rowBase + 64 + srow)*KDIM + sco];
  const i8* Wrow0 = &W[(size_t)(colBase + srow)*KDIM + sco];
  const i8* Wrow1 = &W[(size_t)(colBase + 64 + srow)*KDIM + sco];
  i32x4 c[4][2] = {};
  int aoff[4][2], boff[2][2];
#pragma unroll
  for (int i = 0; i < 4; i++){
    int row = wm*64 + i*16 + rr;
#pragma unroll
    for (int h = 0; h < 2; h++)
      aoff[i][h] = row*128 + (((h*4 + g) ^ (row & 7)) << 4);
  }
#pragma unroll
  for (int j = 0; j < 2; j++){
    int row = wn*32 + j*16 + rr;
#pragma unroll
    for (int h = 0; h < 2; h++)
      boff[j][h] = row*128 + (((h*4 + g) ^ (row & 7)) << 4);
  }
  for (int k0 = 0; k0 < KDIM; k0 += 128){
    __syncthreads();
    GLOAD16(Arow0 + k0, &As[wid*8][0]);
    GLOAD16(Arow1 + k0, &As[64 + wid*8][0]);
    GLOAD16(Wrow0 + k0, &Bs[wid*8][0]);
    GLOAD16(Wrow1 + k0, &Bs[64 + wid*8][0]);
    __syncthreads();
#pragma unroll
    for (int h = 0; h < 2; h++){
      i32x4 af[4], bfr[2];
#pragma unroll
      for (int i = 0; i < 4; i++) af[i]  = *(const i32x4*)((const i8*)As + aoff[i][h]);
#pragma unroll
      for (int j = 0; j < 2; j++) bfr[j] = *(const i32x4*)((const i8*)Bs + boff[j][h]);
#pragma unroll
      for (int i = 0; i < 4; i++)
#pragma unroll
        for (int j = 0; j < 2; j++)
          c[i][j] = MFMAI8(af[i], bfr[j], c[i][j]);
    }
  }
  float lmax = 0.0f;
  const int r0 = (lane >> 4) * 4, ccol = lane & 15;
#pragma unroll
  for (int j = 0; j < 2; j++){
    int col = colBase + wn*32 + j*16 + ccol;
    float rb = rintf(bias[col] / s_b);
#pragma unroll
    for (int i = 0; i < 4; i++){
      int rowb = rowBase + wm*64 + i*16 + r0;
#pragma unroll
      for (int rI = 0; rI < 4; rI++){
        float y = s_b * ((float)c[i][j][rI] + rb);
        out[(size_t)(rowb + rI)*NDIM + col] = y;
        lmax = fmaxf(lmax, fabsf(y));
      }
    }
  }
  lmax = wave_max(lmax);
  if (lane == 0) red[wid] = lmax;
  __syncthreads();
  if (tid == 0){
    float mm = red[0];
#pragma unroll
    for (int i2 = 1; i2 < 8; i2++) mm = fmaxf(mm, red[i2]);
    atomicMax(amax_out, __float_as_int(mm));
  }
}

// QKV projections fused: grid 768 (3 segs x 256 tiles), XCD-chunked swizzle
__global__ __launch_bounds__(512) void k_gemm3(const i8* __restrict__ Xall,
    const i8* __restrict__ Wall, const float* __restrict__ ball,
    float* __restrict__ Yall, const float* __restrict__ sc, int* __restrict__ sci){
  __shared__ i8 As[128][128];
  __shared__ i8 Bs[128][128];
  __shared__ float red[8];
  const int orig = blockIdx.x;
  const int xcd = orig & 7, sl = orig >> 3;
  const int seg = sl >> 5;
  const int t2 = xcd*32 + (sl & 31);
  const int by = t2 >> 3, bx = t2 & 7;
  const float s_x = fmaxf(sc[seg] / 128.0f, EPSF);
  const float s_w = fmaxf(sc[3 + seg] / 127.0f, EPSF);
  gemm_body(Xall + (size_t)seg*NTOK*KDIM, Wall + (size_t)seg*KDIM*NDIM,
            ball + seg*1024, Yall + (size_t)seg*NTOK*NDIM, s_x*s_w,
            by*128, bx*128, sci + 7 + seg, As, Bs, red);
}

// out-projection: grid 256
__global__ __launch_bounds__(512) void k_gemm1(const i8* __restrict__ A,
    const i8* __restrict__ W, const float* __restrict__ bias,
    float* __restrict__ out, const float* __restrict__ sc,
    int sx_slot, int sw_slot, int* __restrict__ amax_out){
  __shared__ i8 As[128][128];
  __shared__ i8 Bs[128][128];
  __shared__ float red[8];
  const int orig = blockIdx.x;
  const int t2 = (orig & 7)*32 + (orig >> 3);
  const int by = t2 >> 3, bx = t2 & 7;
  const float s_x = fmaxf(sc[sx_slot] / 128.0f, EPSF);
  const float s_w = fmaxf(sc[sw_slot] / 127.0f, EPSF);
  gemm_body(A, W, bias, out, s_x*s_w, by*128, bx*128, amax_out, As, Bs, red);
}

// q/k/v f32 (S,B,E) -> qh,kh int8 [BH][S][DH]; vt int8 [BH][DH][S]; vtot[bh][d] = sum_key v
__global__ __launch_bounds__(256) void k_quant_heads(const float* __restrict__ qf,
    const float* __restrict__ kf, const float* __restrict__ vf,
    i8* __restrict__ qh, i8* __restrict__ kh, i8* __restrict__ vt,
    int* __restrict__ vtot, const float* __restrict__ sc){
  const float s_q = fmaxf((sc[7]*0.125f)/128.0f, EPSF);  // scale of q/sqrt(64)
  const float s_k = fmaxf(sc[8]/128.0f, EPSF);
  const float s_v = fmaxf(sc[9]/128.0f, EPSF);
  __shared__ i8 tile[64][68];
  const int bx = blockIdx.x;
  const int st = bx & 15, hh = (bx >> 4) & 15, b = bx >> 8;
  const int t = threadIdx.x;
  const int sl = t >> 2, dc = (t & 3) * 16;
  const size_t row = (size_t)(st*64 + sl)*BATCH + b;
  const size_t ibase = row*EMB + hh*DHEAD + dc;
  const int bh = b*NH + hh;
  float vq[16], vk[16], vv[16];
#pragma unroll
  for (int i = 0; i < 4; i++){
    *(float4*)&vq[i*4] = *(const float4*)&qf[ibase + i*4];
    *(float4*)&vk[i*4] = *(const float4*)&kf[ibase + i*4];
    *(float4*)&vv[i*4] = *(const float4*)&vf[ibase + i*4];
  }
  alignas(16) i8 oq[16], ok[16];
#pragma unroll
  for (int i = 0; i < 16; i++){
    float tq = fminf(fmaxf(rintf((vq[i]*0.125f)/s_q), -128.f), 127.f);
    float tk = fminf(fmaxf(rintf(vk[i]/s_k), -128.f), 127.f);
    float tv = fminf(fmaxf(rintf(vv[i]/s_v), -128.f), 127.f);
    oq[i] = (i8)(int)tq; ok[i] = (i8)(int)tk;
    tile[dc + i][sl] = (i8)(int)tv;
  }
  const size_t qoff = ((size_t)bh*S_LEN + st*64 + sl)*DHEAD + dc;
  *(int4*)&qh[qoff] = *(const int4*)&oq[0];
  *(int4*)&kh[qoff] = *(const int4*)&ok[0];
  __syncthreads();
  const int d = t >> 2, sc4 = (t & 3) * 16;
  int ovi[4];
  int sum = 0;
#pragma unroll
  for (int w4 = 0; w4 < 4; w4++){
    unsigned x = *(const unsigned*)&tile[d][sc4 + w4*4];
    ovi[w4] = (int)x;
#pragma unroll
    for (int bb = 0; bb < 4; bb++) sum += (int)(i8)(x >> (8*bb));
  }
  const size_t voff = ((size_t)bh*DHEAD + d)*S_LEN + st*64 + sc4;
  *(int4*)&vt[voff] = *(const int4*)&ovi[0];
  sum += __shfl_xor(sum, 1);
  sum += __shfl_xor(sum, 2);
  if ((t & 3) == 0) atomicAdd(&vtot[bh*DHEAD + d], sum);
}

// attention pass 1: KVBLK=128, 4 waves / 64 q-rows, grid 1024. SWAPPED int8 QK^T,
// online (m,l) in log2 domain; per-lane scalars.
__global__ __launch_bounds__(256) void k_attn1(const i8* __restrict__ qh,
    const i8* __restrict__ kh, float* __restrict__ mrow, float* __restrict__ lrow,
    const float* __restrict__ sc, int* __restrict__ sci){
  __shared__ i8 Ks[128][64];
  __shared__ float red2[4];
  const int orig = blockIdx.x;
  const int tile = (orig & 7) * 128 + (orig >> 3);   // XCD-chunked swizzle
  const int bhead = tile >> 4, q0 = (tile & 15) * 64;
  const int tid = threadIdx.x, w = tid >> 6, lane = tid & 63;
  const int rr = lane & 15, g = lane >> 4;
  const float s_q = fmaxf((sc[7]*0.125f)/128.0f, EPSF);
  const float s_k = fmaxf(sc[8]/128.0f, EPSF);
  const float C1 = s_q * s_k * LOG2E;                // scores scaled to log2 domain
  const i8* qbase = qh + ((size_t)bhead*S_LEN + q0 + w*16)*DHEAD;
  const i8* kbase = kh + (size_t)bhead*S_LEN*DHEAD;
  i32x4 a = *(const i32x4*)&qbase[rr*DHEAD + g*16];  // Q fragment (B operand)
  // staging: wave w stages Ks rows w*32..w*32+31 (2 gloads of 16 rows)
  const int ksel = ((lane & 3) ^ ((lane >> 3) & 3)) << 4;   // lane-only source sel
  const int kr = lane >> 2;                                  // 0..15
  float m = -1e30f, l = 0.0f;
  for (int cch = 0; cch < 8; cch++){
    const int n0 = cch * 128;
    __syncthreads();
    GLOAD16(&kbase[(size_t)(n0 + w*32 + kr)*DHEAD + ksel],      &Ks[w*32][0]);
    GLOAD16(&kbase[(size_t)(n0 + w*32 + 16 + kr)*DHEAD + ksel], &Ks[w*32 + 16][0]);
    __syncthreads();
    float sv[8][4];
#pragma unroll
    for (int nt = 0; nt < 8; nt++){
      int row = nt*16 + rr;
      i32x4 b = *(const i32x4*)((const i8*)Ks + row*64 + (((g ^ ((row >> 1) & 3))) << 4));
      i32x4 acc = {};
      acc = MFMAI8(b, a, acc);                       // SWAPPED: D[key][q]
#pragma unroll
      for (int r = 0; r < 4; r++) sv[nt][r] = (float)acc[r]*C1;
    }
    float cm = sv[0][0];
#pragma unroll
    for (int nt = 0; nt < 8; nt++)
#pragma unroll
      for (int r = 0; r < 4; r++) cm = fmaxf(cm, sv[nt][r]);
    float mn = fmaxf(m, cm);
    l *= EXP2F(m - mn);                              // 1.0 when max unchanged
    m = mn;
#pragma unroll
    for (int nt = 0; nt < 8; nt++)
#pragma unroll
      for (int r = 0; r < 4; r++) l += EXP2F(sv[nt][r] - m);
  }
  // merge (m,l) across the 4 g-lanes sharing q-row rr
#pragma unroll
  for (int off = 16; off < 64; off <<= 1){
    float mo = __shfl_xor(m, off), lo = __shfl_xor(l, off);
    float mn = fmaxf(m, mo);
    l = l*EXP2F(m - mn) + lo*EXP2F(mo - mn);
    m = mn;
  }
  if (g == 0){
    mrow[(size_t)bhead*S_LEN + q0 + w*16 + rr] = m;  // log2-domain max
    lrow[(size_t)bhead*S_LEN + q0 + w*16 + rr] = l;
  }
  float im = wave_max(1.0f / l);
  if (lane == 0) red2[w] = im;
  __syncthreads();
  if (tid == 0){
    float mm = fmaxf(fmaxf(red2[0], red2[1]), fmaxf(red2[2], red2[3]));
    atomicMax(sci + 13, __float_as_int(mm));
  }
}

// attention pass 2: KVBLK=128. SWAPPED int8 QK^T + int8 PV with -128 offset.
// Ks[128][64]; Vs[64][128] with chunk^=(row&7) involution (128B rows); P[4][16][136].
__global__ __launch_bounds__(256) void k_attn2(const i8* __restrict__ qh,
    const i8* __restrict__ kh, const i8* __restrict__ vt,
    const float* __restrict__ mrow, const float* __restrict__ lrow,
    const int* __restrict__ vtot, float* __restrict__ aout,
    const float* __restrict__ sc, const int* __restrict__ sci,
    int* __restrict__ amax_out){
  __shared__ i8 Ks[128][64];
  __shared__ i8 Vs[64][128];
  __shared__ i8 P[4][16][136];
  __shared__ float red[4];
  const int orig = blockIdx.x;
  const int tile = (orig & 7) * 128 + (orig >> 3);   // XCD-chunked swizzle
  const int bhead = tile >> 4, q0 = (tile & 15) * 64;
  const int tid = threadIdx.x, w = tid >> 6, lane = tid & 63;
  const int rr = lane & 15, g = lane >> 4;
  const float s_q = fmaxf((sc[7]*0.125f)/128.0f, EPSF);
  const float s_k = fmaxf(sc[8]/128.0f, EPSF);
  const float C1 = s_q * s_k * LOG2E;
  const float s_v = fmaxf(sc[9]/128.0f, EPSF);
  const float s_a = fmaxf(__int_as_float(sci[13]) / 255.0f, EPSF);
  const float fac = s_a * s_v;
  const i8* qbase = qh + ((size_t)bhead*S_LEN + q0 + w*16)*DHEAD;
  const i8* kbase = kh + (size_t)bhead*S_LEN*DHEAD;
  const i8* vbase = vt + (size_t)bhead*DHEAD*S_LEN;
  i32x4 a = *(const i32x4*)&qbase[rr*DHEAD + g*16];  // Q fragment (B operand)
  // per-lane scalars for q-row rr: nb = log2(inv) - m  (inv folded into exponent)
  float nb;
  {
    size_t qr = (size_t)bhead*S_LEN + q0 + w*16 + rr;
    float inv = 1.0f / (lrow[qr] * s_a);
    nb = log2f(inv) - mrow[qr];
  }
  // K staging: wave w stages rows w*32..w*32+31; lane-only selector
  const int ksel = ((lane & 3) ^ ((lane >> 3) & 3)) << 4;
  const int kr = lane >> 2;                    // 0..15
  // V staging: wave w stages d-rows w*16..w*16+15; 128B rows, chunk^=(row&7)
  const int vsel = (((lane & 7) ^ ((lane >> 3) & 7)) << 4);
  const int vr = lane >> 3;                    // 0..7
  i32x4 cpv[4] = {};
  for (int cch = 0; cch < 8; cch++){
    const int n0 = cch * 128;
    __syncthreads();
    GLOAD16(&kbase[(size_t)(n0 + w*32 + kr)*DHEAD + ksel],      &Ks[w*32][0]);
    GLOAD16(&kbase[(size_t)(n0 + w*32 + 16 + kr)*DHEAD + ksel], &Ks[w*32 + 16][0]);
    GLOAD16(&vbase[(size_t)(w*16 + vr)*S_LEN + n0 + vsel],      &Vs[w*16][0]);
    GLOAD16(&vbase[(size_t)(w*16 + 8 + vr)*S_LEN + n0 + vsel],  &Vs[w*16 + 8][0]);
    __syncthreads();
#pragma unroll
    for (int nt = 0; nt < 8; nt++){
      int row = nt*16 + rr;
      i32x4 b = *(const i32x4*)((const i8*)Ks + row*64 + (((g ^ ((row >> 1) & 3))) << 4));
      i32x4 acc = {};
      acc = MFMAI8(b, a, acc);                       // SWAPPED: D[key][q]
      unsigned pw = 0;
#pragma unroll
      for (int r = 0; r < 4; r++){
        float e  = EXP2F(fmaf((float)acc[r], C1, nb));
        int   pq = (int)fminf(rintf(e), 255.0f);
        pw |= (unsigned)pq << (8*r);
      }
      pw ^= 0x80808080u;                             // -128 per byte
      *(unsigned*)&P[w][rr][nt*16 + g*4] = pw;
    }
    // PV: within-wave P dependency (lgkmcnt orders write->read; no barrier needed)
#pragma unroll
    for (int h = 0; h < 2; h++){
      i32x4 pa;
      {
        const i8* pptr = &P[w][rr][h*64 + g*16];
        pa[0] = *(const int*)(pptr + 0);
        pa[1] = *(const int*)(pptr + 4);
        pa[2] = *(const int*)(pptr + 8);
        pa[3] = *(const int*)(pptr + 12);
      }
#pragma unroll
      for (int f = 0; f < 4; f++){
        int row = f*16 + rr;
        i32x4 bv = *(const i32x4*)((const i8*)Vs + row*128 + (((h*4 + g) ^ (row & 7)) << 4));
        cpv[f] = MFMAI8(pa, bv, cpv[f]);
      }
    }
  }
  const int b = bhead >> 4, hh = bhead & 15;
  float lmax = 0.0f;
#pragma unroll
  for (int f = 0; f < 4; f++){
    int d = f*16 + rr;
    int vcorr = 128 * vtot[bhead*DHEAD + d];
#pragma unroll
    for (int r = 0; r < 4; r++){
      int srow2 = q0 + w*16 + g*4 + r;
      float y = fac * (float)(cpv[f][r] + vcorr);
      aout[(size_t)(srow2*BATCH + b)*EMB + hh*DHEAD + d] = y;
      lmax = fmaxf(lmax, fabsf(y));
    }
  }
  lmax = wave_max(lmax);
  __syncthreads();
  if (lane == 0) red[w] = lmax;
  __syncthreads();
  if (tid == 0){
    float mm = fmaxf(fmaxf(red[0], red[1]), fmaxf(red[2], red[3]));
    atomicMax(amax_out, __float_as_int(mm));
  }
}

extern "C" void kernel_launch(void* const* d_in, const int* in_sizes, int n_in,
                              void* d_out, int out_size, void* d_ws, size_t ws_size,
                              hipStream_t stream){
  const float* query = (const float*)d_in[0];
  const float* key   = (const float*)d_in[1];
  const float* value = (const float*)d_in[2];
  const float* inW   = (const float*)d_in[3];
  const float* inB   = (const float*)d_in[4];
  const float* outW  = (const float*)d_in[5];
  const float* outB  = (const float*)d_in[6];
  float* out = (float*)d_out;

  char* ws = (char*)d_ws;
  float* sc  = (float*)ws;
  int*   sci = (int*)ws;
  int*   vtotI = (int*)(ws + 256);               // 64x64 i32 = 16 KB
  u8* WQQ = (u8*)(ws + 256 + 16384);             // weights int8, 1MB each
  u8* WKQ = WQQ + 1024*1024;
  u8* WVQ = WKQ + 1024*1024;
  u8* WOQ = WVQ + 1024*1024;
  u8* XQ  = WOQ + 1024*1024;                     // acts int8, 4MB each
  u8* XK  = XQ + (size_t)NTOK*1024;
  u8* XV  = XK + (size_t)NTOK*1024;
  float* QF = (float*)(XV + (size_t)NTOK*1024);  // f32, 16MB each
  float* KF = QF + (size_t)NTOK*1024;
  float* VF = KF + (size_t)NTOK*1024;
  i8* VT = (i8*)(VF + (size_t)NTOK*1024);        // int8 V^T, 4MB
  float* MROW = (float*)(VT + (size_t)BHEAD*DHEAD*S_LEN);
  float* LROW = MROW + BHEAD*S_LEN;
  // reuse (lifetimes are disjoint along the serial stream):
  i8* QH  = (i8*)XQ;   i8* KH = (i8*)XK;         // proj-input quants dead after GEMMs
  float* AOUT = QF;                              // q f32 dead after k_quant_heads
  u8* AOQ = XV;                                  // v int8 input dead after gemm3

  AQTable tab;
  tab.d[0] = { query,             XQ,  NTOK*1024/4, 0, 128.f, -128.f };
  tab.d[1] = { key,               XK,  NTOK*1024/4, 1, 128.f, -128.f };
  tab.d[2] = { value,             XV,  NTOK*1024/4, 2, 128.f, -128.f };
  tab.d[3] = { inW,               WQQ, 1024*1024/4, 3, 127.f, -127.f };
  tab.d[4] = { inW + 1024*1024,   WKQ, 1024*1024/4, 4, 127.f, -127.f };
  tab.d[5] = { inW + 2*1024*1024, WVQ, 1024*1024/4, 5, 127.f, -127.f };
  tab.d[6] = { outW,              WOQ, 1024*1024/4, 6, 127.f, -127.f };

  k_zero<<<17, 256, 0, stream>>>(sc, vtotI);
  k_absmax7<<<2048, 256, 0, stream>>>(tab, sci);
  k_quant7<<<2048, 256, 0, stream>>>(tab, sc);
  k_gemm3<<<768, 512, 0, stream>>>((const i8*)XQ, (const i8*)WQQ, inB, QF, sc, sci);
  k_quant_heads<<<1024, 256, 0, stream>>>(QF, KF, VF, QH, KH, VT, vtotI, sc);
  k_attn1<<<1024, 256, 0, stream>>>(QH, KH, MROW, LROW, sc, sci);
  k_attn2<<<1024, 256, 0, stream>>>(QH, KH, VT, MROW, LROW, vtotI, AOUT, sc, sci, sci + 10);
  k_quant<<<1024, 256, 0, stream>>>(AOUT, AOQ, NTOK*1024/4, sc, 10);
  k_gemm1<<<256, 512, 0, stream>>>((const i8*)AOQ, (const i8*)WOQ, outB, out, sc, 10, 6, sci + 12);
}

// Round 15
// 178.951 us; speedup vs baseline: 1.1699x; 1.0175x over previous
//
#include <hip/hip_runtime.h>
#include <stdint.h>

typedef unsigned short u16;
typedef signed char i8;
typedef unsigned char u8;
typedef __attribute__((ext_vector_type(8))) short bf16x8;
typedef __attribute__((ext_vector_type(4))) float f32x4;
typedef __attribute__((ext_vector_type(4))) int i32x4;

#define S_LEN 1024
#define BATCH 4
#define EMB   1024
#define NH    16
#define DHEAD 64
#define BHEAD 64
#define NTOK  4096
#define KDIM  1024
#define NDIM  1024
#define EPSF  1e-8f
#define LOG2E 1.4426950408889634f

#define MFMAI8(a,b,c)  __builtin_amdgcn_mfma_i32_16x16x64_i8((a),(b),(c),0,0,0)

#define GLOAD16(g, l) __builtin_amdgcn_global_load_lds( \
    (const __attribute__((address_space(1))) void*)(g), \
    (__attribute__((address_space(3))) void*)(l), 16, 0, 0)

#define EXP2F(x) __builtin_amdgcn_exp2f(x)

__device__ __forceinline__ unsigned pack4(float a, float b, float c, float d){
  int qa = (int)a, qb = (int)b, qc = (int)c, qd = (int)d;
  return (unsigned)(qa & 255) | ((unsigned)(qb & 255) << 8) |
         ((unsigned)(qc & 255) << 16) | ((unsigned)(qd & 255) << 24);
}

__device__ __forceinline__ float wave_max(float v){
#pragma unroll
  for (int off = 32; off > 0; off >>= 1) v = fmaxf(v, __shfl_xor(v, off));
  return v;
}

// ---------------- scale slots ----------------
// 0 amax_query 1 amax_key 2 amax_value 3 amax_Wq 4 amax_Wk 5 amax_Wv 6 amax_Wo
// 7 amax_qproj 8 amax_kproj 9 amax_vproj 10 amax_attnout 11 unused 12 dummy 13 inv_l_max

// zero sc[0..15] and vtot[4096]
__global__ __launch_bounds__(256) void k_zero(float* sc, int* vtot){
  if (blockIdx.x == 0){
    if (threadIdx.x < 16) sc[threadIdx.x] = 0.0f;
  } else {
    vtot[(blockIdx.x - 1)*256 + threadIdx.x] = 0;
  }
}

struct AQDesc { const float* x; u8* y; int n4; int slot; float qdiv; float lo; };
struct AQTable { AQDesc d[7]; };

// merged absmax over 7 tensors; grid = 2048. Every segment is EXACTLY 8 iterations:
// q/k/v: 1M float4 / (512 blk * 256 thr) = 8; weights: 256K / (128*256) = 8.
// Static trip count -> 8 in-flight loads per thread (ILP; the dynamic loop was 4x off BW).
__global__ __launch_bounds__(256) void k_absmax7(AQTable t, int* __restrict__ sci){
  const int bid = blockIdx.x;
  int seg, b0, nb;
  if (bid < 1536){ seg = bid >> 9; b0 = seg << 9; nb = 512; }
  else { seg = 3 + ((bid - 1536) >> 7); b0 = 1536 + ((seg - 3) << 7); nb = 128; }
  const AQDesc D = t.d[seg];
  const float4* x4 = (const float4*)D.x;
  const int base = (bid - b0)*256 + threadIdx.x;
  const int stride = nb*256;
  float4 v[8];
#pragma unroll
  for (int it = 0; it < 8; it++) v[it] = x4[base + it*stride];
  float m = 0.0f;
#pragma unroll
  for (int it = 0; it < 8; it++)
    m = fmaxf(m, fmaxf(fmaxf(fabsf(v[it].x), fabsf(v[it].y)),
                       fmaxf(fabsf(v[it].z), fabsf(v[it].w))));
  m = wave_max(m);
  __shared__ float red[4];
  int lane = threadIdx.x & 63, w = threadIdx.x >> 6;
  if (lane == 0) red[w] = m;
  __syncthreads();
  if (threadIdx.x == 0){
    float mm = fmaxf(fmaxf(red[0], red[1]), fmaxf(red[2], red[3]));
    atomicMax(sci + D.slot, __float_as_int(mm));
  }
}

// merged fake-quant of 7 tensors to int8 grid; same static 8-iteration structure
__global__ __launch_bounds__(256) void k_quant7(AQTable t, const float* __restrict__ sc){
  const int bid = blockIdx.x;
  int seg, b0, nb;
  if (bid < 1536){ seg = bid >> 9; b0 = seg << 9; nb = 512; }
  else { seg = 3 + ((bid - 1536) >> 7); b0 = 1536 + ((seg - 3) << 7); nb = 128; }
  const AQDesc D = t.d[seg];
  const float s = fmaxf(sc[D.slot] / D.qdiv, EPSF);
  const float lo = D.lo;
  const float4* x4 = (const float4*)D.x;
  unsigned* y4 = (unsigned*)D.y;
  const int base = (bid - b0)*256 + threadIdx.x;
  const int stride = nb*256;
  float4 v[8];
#pragma unroll
  for (int it = 0; it < 8; it++) v[it] = x4[base + it*stride];
#pragma unroll
  for (int it = 0; it < 8; it++){
    float t0 = fminf(fmaxf(rintf(v[it].x / s), lo), 127.f);
    float t1 = fminf(fmaxf(rintf(v[it].y / s), lo), 127.f);
    float t2 = fminf(fmaxf(rintf(v[it].z / s), lo), 127.f);
    float t3 = fminf(fmaxf(rintf(v[it].w / s), lo), 127.f);
    y4[base + it*stride] = pack4(t0, t1, t2, t3);
  }
}

// single-tensor quant to int8 (attention output); grid 1024 -> exactly 4 iterations
__global__ __launch_bounds__(256) void k_quant(const float* __restrict__ x,
    u8* __restrict__ y, const float* __restrict__ sc, int slot){
  const float s = fmaxf(sc[slot] / 128.0f, EPSF);
  const float4* x4 = (const float4*)x;
  unsigned* y4 = (unsigned*)y;
  const int base = blockIdx.x*256 + threadIdx.x;
  const int stride = 1024*256;
  float4 v[4];
#pragma unroll
  for (int it = 0; it < 4; it++) v[it] = x4[base + it*stride];
#pragma unroll
  for (int it = 0; it < 4; it++){
    float t0 = fminf(fmaxf(rintf(v[it].x / s), -128.f), 127.f);
    float t1 = fminf(fmaxf(rintf(v[it].y / s), -128.f), 127.f);
    float t2 = fminf(fmaxf(rintf(v[it].z / s), -128.f), 127.f);
    float t3 = fminf(fmaxf(rintf(v[it].w / s), -128.f), 127.f);
    y4[base + it*stride] = pack4(t0, t1, t2, t3);
  }
}

// ---------------- GEMM: 128x128 tile, BK=128 int8, 8 waves, 2-barrier + swizzle ----
__device__ __forceinline__ void gemm_body(const i8* __restrict__ A,
    const i8* __restrict__ W, const float* __restrict__ bias,
    float* __restrict__ out, float s_b, int rowBase, int colBase,
    int* __restrict__ amax_out, i8 (*As)[128], i8 (*Bs)[128], float* red){
  const int tid = threadIdx.x;
  const int wid = tid >> 6, lane = tid & 63;
  const int wm = wid >> 2, wn = wid & 3;
  const int rr = lane & 15, g = lane >> 4;
  const int srow = wid*8 + (lane >> 3);
  const int sco  = ((lane & 7) ^ (lane >> 3)) << 4;
  const i8* Arow0 = &A[(size_t)(rowBase + srow)*KDIM + sco];
  const i8* Arow1 = &A[(size_t)(rowBase + 64 + srow)*KDIM + sco];
  const i8* Wrow0 = &W[(size_t)(colBase + srow)*KDIM + sco];
  const i8* Wrow1 = &W[(size_t)(colBase + 64 + srow)*KDIM + sco];
  i32x4 c[4][2] = {};
  int aoff[4][2], boff[2][2];
#pragma unroll
  for (int i = 0; i < 4; i++){
    int row = wm*64 + i*16 + rr;
#pragma unroll
    for (int h = 0; h < 2; h++)
      aoff[i][h] = row*128 + (((h*4 + g) ^ (row & 7)) << 4);
  }
#pragma unroll
  for (int j = 0; j < 2; j++){
    int row = wn*32 + j*16 + rr;
#pragma unroll
    for (int h = 0; h < 2; h++)
      boff[j][h] = row*128 + (((h*4 + g) ^ (row & 7)) << 4);
  }
  for (int k0 = 0; k0 < KDIM; k0 += 128){
    __syncthreads();
    GLOAD16(Arow0 + k0, &As[wid*8][0]);
    GLOAD16(Arow1 + k0, &As[64 + wid*8][0]);
    GLOAD16(Wrow0 + k0, &Bs[wid*8][0]);
    GLOAD16(Wrow1 + k0, &Bs[64 + wid*8][0]);
    __syncthreads();
#pragma unroll
    for (int h = 0; h < 2; h++){
      i32x4 af[4], bfr[2];
#pragma unroll
      for (int i = 0; i < 4; i++) af[i]  = *(const i32x4*)((const i8*)As + aoff[i][h]);
#pragma unroll
      for (int j = 0; j < 2; j++) bfr[j] = *(const i32x4*)((const i8*)Bs + boff[j][h]);
#pragma unroll
      for (int i = 0; i < 4; i++)
#pragma unroll
        for (int j = 0; j < 2; j++)
          c[i][j] = MFMAI8(af[i], bfr[j], c[i][j]);
    }
  }
  float lmax = 0.0f;
  const int r0 = (lane >> 4) * 4, ccol = lane & 15;
#pragma unroll
  for (int j = 0; j < 2; j++){
    int col = colBase + wn*32 + j*16 + ccol;
    float rb = rintf(bias[col] / s_b);
#pragma unroll
    for (int i = 0; i < 4; i++){
      int rowb = rowBase + wm*64 + i*16 + r0;
#pragma unroll
      for (int rI = 0; rI < 4; rI++){
        float y = s_b * ((float)c[i][j][rI] + rb);
        out[(size_t)(rowb + rI)*NDIM + col] = y;
        lmax = fmaxf(lmax, fabsf(y));
      }
    }
  }
  lmax = wave_max(lmax);
  if (lane == 0) red[wid] = lmax;
  __syncthreads();
  if (tid == 0){
    float mm = red[0];
#pragma unroll
    for (int i2 = 1; i2 < 8; i2++) mm = fmaxf(mm, red[i2]);
    atomicMax(amax_out, __float_as_int(mm));
  }
}

// QKV projections fused: grid 768 (3 segs x 256 tiles), XCD-chunked swizzle
__global__ __launch_bounds__(512) void k_gemm3(const i8* __restrict__ Xall,
    const i8* __restrict__ Wall, const float* __restrict__ ball,
    float* __restrict__ Yall, const float* __restrict__ sc, int* __restrict__ sci){
  __shared__ i8 As[128][128];
  __shared__ i8 Bs[128][128];
  __shared__ float red[8];
  const int orig = blockIdx.x;
  const int xcd = orig & 7, sl = orig >> 3;
  const int seg = sl >> 5;
  const int t2 = xcd*32 + (sl & 31);
  const int by = t2 >> 3, bx = t2 & 7;
  const float s_x = fmaxf(sc[seg] / 128.0f, EPSF);
  const float s_w = fmaxf(sc[3 + seg] / 127.0f, EPSF);
  gemm_body(Xall + (size_t)seg*NTOK*KDIM, Wall + (size_t)seg*KDIM*NDIM,
            ball + seg*1024, Yall + (size_t)seg*NTOK*NDIM, s_x*s_w,
            by*128, bx*128, sci + 7 + seg, As, Bs, red);
}

// out-projection: grid 256
__global__ __launch_bounds__(512) void k_gemm1(const i8* __restrict__ A,
    const i8* __restrict__ W, const float* __restrict__ bias,
    float* __restrict__ out, const float* __restrict__ sc,
    int sx_slot, int sw_slot, int* __restrict__ amax_out){
  __shared__ i8 As[128][128];
  __shared__ i8 Bs[128][128];
  __shared__ float red[8];
  const int orig = blockIdx.x;
  const int t2 = (orig & 7)*32 + (orig >> 3);
  const int by = t2 >> 3, bx = t2 & 7;
  const float s_x = fmaxf(sc[sx_slot] / 128.0f, EPSF);
  const float s_w = fmaxf(sc[sw_slot] / 127.0f, EPSF);
  gemm_body(A, W, bias, out, s_x*s_w, by*128, bx*128, amax_out, As, Bs, red);
}

// q/k/v f32 (S,B,E) -> qh,kh int8 [BH][S][DH]; vt int8 [BH][DH][S]; vtot[bh][d] = sum_key v
__global__ __launch_bounds__(256) void k_quant_heads(const float* __restrict__ qf,
    const float* __restrict__ kf, const float* __restrict__ vf,
    i8* __restrict__ qh, i8* __restrict__ kh, i8* __restrict__ vt,
    int* __restrict__ vtot, const float* __restrict__ sc){
  const float s_q = fmaxf((sc[7]*0.125f)/128.0f, EPSF);  // scale of q/sqrt(64)
  const float s_k = fmaxf(sc[8]/128.0f, EPSF);
  const float s_v = fmaxf(sc[9]/128.0f, EPSF);
  __shared__ i8 tile[64][68];
  const int bx = blockIdx.x;
  const int st = bx & 15, hh = (bx >> 4) & 15, b = bx >> 8;
  const int t = threadIdx.x;
  const int sl = t >> 2, dc = (t & 3) * 16;
  const size_t row = (size_t)(st*64 + sl)*BATCH + b;
  const size_t ibase = row*EMB + hh*DHEAD + dc;
  const int bh = b*NH + hh;
  float vq[16], vk[16], vv[16];
#pragma unroll
  for (int i = 0; i < 4; i++){
    *(float4*)&vq[i*4] = *(const float4*)&qf[ibase + i*4];
    *(float4*)&vk[i*4] = *(const float4*)&kf[ibase + i*4];
    *(float4*)&vv[i*4] = *(const float4*)&vf[ibase + i*4];
  }
  alignas(16) i8 oq[16], ok[16];
#pragma unroll
  for (int i = 0; i < 16; i++){
    float tq = fminf(fmaxf(rintf((vq[i]*0.125f)/s_q), -128.f), 127.f);
    float tk = fminf(fmaxf(rintf(vk[i]/s_k), -128.f), 127.f);
    float tv = fminf(fmaxf(rintf(vv[i]/s_v), -128.f), 127.f);
    oq[i] = (i8)(int)tq; ok[i] = (i8)(int)tk;
    tile[dc + i][sl] = (i8)(int)tv;
  }
  const size_t qoff = ((size_t)bh*S_LEN + st*64 + sl)*DHEAD + dc;
  *(int4*)&qh[qoff] = *(const int4*)&oq[0];
  *(int4*)&kh[qoff] = *(const int4*)&ok[0];
  __syncthreads();
  const int d = t >> 2, sc4 = (t & 3) * 16;
  int ovi[4];
  int sum = 0;
#pragma unroll
  for (int w4 = 0; w4 < 4; w4++){
    unsigned x = *(const unsigned*)&tile[d][sc4 + w4*4];
    ovi[w4] = (int)x;
#pragma unroll
    for (int bb = 0; bb < 4; bb++) sum += (int)(i8)(x >> (8*bb));
  }
  const size_t voff = ((size_t)bh*DHEAD + d)*S_LEN + st*64 + sc4;
  *(int4*)&vt[voff] = *(const int4*)&ovi[0];
  sum += __shfl_xor(sum, 1);
  sum += __shfl_xor(sum, 2);
  if ((t & 3) == 0) atomicAdd(&vtot[bh*DHEAD + d], sum);
}

// attention pass 1: KVBLK=128, 4 waves / 64 q-rows, grid 1024. SWAPPED int8 QK^T,
// online (m,l) in log2 domain; per-lane scalars.
__global__ __launch_bounds__(256) void k_attn1(const i8* __restrict__ qh,
    const i8* __restrict__ kh, float* __restrict__ mrow, float* __restrict__ lrow,
    const float* __restrict__ sc, int* __restrict__ sci){
  __shared__ i8 Ks[128][64];
  __shared__ float red2[4];
  const int orig = blockIdx.x;
  const int tile = (orig & 7) * 128 + (orig >> 3);   // XCD-chunked swizzle
  const int bhead = tile >> 4, q0 = (tile & 15) * 64;
  const int tid = threadIdx.x, w = tid >> 6, lane = tid & 63;
  const int rr = lane & 15, g = lane >> 4;
  const float s_q = fmaxf((sc[7]*0.125f)/128.0f, EPSF);
  const float s_k = fmaxf(sc[8]/128.0f, EPSF);
  const float C1 = s_q * s_k * LOG2E;                // scores scaled to log2 domain
  const i8* qbase = qh + ((size_t)bhead*S_LEN + q0 + w*16)*DHEAD;
  const i8* kbase = kh + (size_t)bhead*S_LEN*DHEAD;
  i32x4 a = *(const i32x4*)&qbase[rr*DHEAD + g*16];  // Q fragment (B operand)
  // staging: wave w stages Ks rows w*32..w*32+31 (2 gloads of 16 rows)
  const int ksel = ((lane & 3) ^ ((lane >> 3) & 3)) << 4;   // lane-only source sel
  const int kr = lane >> 2;                                  // 0..15
  float m = -1e30f, l = 0.0f;
  for (int cch = 0; cch < 8; cch++){
    const int n0 = cch * 128;
    __syncthreads();
    GLOAD16(&kbase[(size_t)(n0 + w*32 + kr)*DHEAD + ksel],      &Ks[w*32][0]);
    GLOAD16(&kbase[(size_t)(n0 + w*32 + 16 + kr)*DHEAD + ksel], &Ks[w*32 + 16][0]);
    __syncthreads();
    float sv[8][4];
#pragma unroll
    for (int nt = 0; nt < 8; nt++){
      int row = nt*16 + rr;
      i32x4 b = *(const i32x4*)((const i8*)Ks + row*64 + (((g ^ ((row >> 1) & 3))) << 4));
      i32x4 acc = {};
      acc = MFMAI8(b, a, acc);                       // SWAPPED: D[key][q]
#pragma unroll
      for (int r = 0; r < 4; r++) sv[nt][r] = (float)acc[r]*C1;
    }
    float cm = sv[0][0];
#pragma unroll
    for (int nt = 0; nt < 8; nt++)
#pragma unroll
      for (int r = 0; r < 4; r++) cm = fmaxf(cm, sv[nt][r]);
    float mn = fmaxf(m, cm);
    l *= EXP2F(m - mn);                              // 1.0 when max unchanged
    m = mn;
#pragma unroll
    for (int nt = 0; nt < 8; nt++)
#pragma unroll
      for (int r = 0; r < 4; r++) l += EXP2F(sv[nt][r] - m);
  }
  // merge (m,l) across the 4 g-lanes sharing q-row rr
#pragma unroll
  for (int off = 16; off < 64; off <<= 1){
    float mo = __shfl_xor(m, off), lo = __shfl_xor(l, off);
    float mn = fmaxf(m, mo);
    l = l*EXP2F(m - mn) + lo*EXP2F(mo - mn);
    m = mn;
  }
  if (g == 0){
    mrow[(size_t)bhead*S_LEN + q0 + w*16 + rr] = m;  // log2-domain max
    lrow[(size_t)bhead*S_LEN + q0 + w*16 + rr] = l;
  }
  float im = wave_max(1.0f / l);
  if (lane == 0) red2[w] = im;
  __syncthreads();
  if (tid == 0){
    float mm = fmaxf(fmaxf(red2[0], red2[1]), fmaxf(red2[2], red2[3]));
    atomicMax(sci + 13, __float_as_int(mm));
  }
}

// attention pass 2: KVBLK=128. SWAPPED int8 QK^T + int8 PV with -128 offset.
// Ks[128][64]; Vs[64][128] with chunk^=(row&7) involution (128B rows); P[4][16][136].
__global__ __launch_bounds__(256) void k_attn2(const i8* __restrict__ qh,
    const i8* __restrict__ kh, const i8* __restrict__ vt,
    const float* __restrict__ mrow, const float* __restrict__ lrow,
    const int* __restrict__ vtot, float* __restrict__ aout,
    const float* __restrict__ sc, const int* __restrict__ sci,
    int* __restrict__ amax_out){
  __shared__ i8 Ks[128][64];
  __shared__ i8 Vs[64][128];
  __shared__ i8 P[4][16][136];
  __shared__ float red[4];
  const int orig = blockIdx.x;
  const int tile = (orig & 7) * 128 + (orig >> 3);   // XCD-chunked swizzle
  const int bhead = tile >> 4, q0 = (tile & 15) * 64;
  const int tid = threadIdx.x, w = tid >> 6, lane = tid & 63;
  const int rr = lane & 15, g = lane >> 4;
  const float s_q = fmaxf((sc[7]*0.125f)/128.0f, EPSF);
  const float s_k = fmaxf(sc[8]/128.0f, EPSF);
  const float C1 = s_q * s_k * LOG2E;
  const float s_v = fmaxf(sc[9]/128.0f, EPSF);
  const float s_a = fmaxf(__int_as_float(sci[13]) / 255.0f, EPSF);
  const float fac = s_a * s_v;
  const i8* qbase = qh + ((size_t)bhead*S_LEN + q0 + w*16)*DHEAD;
  const i8* kbase = kh + (size_t)bhead*S_LEN*DHEAD;
  const i8* vbase = vt + (size_t)bhead*DHEAD*S_LEN;
  i32x4 a = *(const i32x4*)&qbase[rr*DHEAD + g*16];  // Q fragment (B operand)
  // per-lane scalars for q-row rr: nb = log2(inv) - m  (inv folded into exponent)
  float nb;
  {
    size_t qr = (size_t)bhead*S_LEN + q0 + w*16 + rr;
    float inv = 1.0f / (lrow[qr] * s_a);
    nb = log2f(inv) - mrow[qr];
  }
  // K staging: wave w stages rows w*32..w*32+31; lane-only selector
  const int ksel = ((lane & 3) ^ ((lane >> 3) & 3)) << 4;
  const int kr = lane >> 2;                    // 0..15
  // V staging: wave w stages d-rows w*16..w*16+15; 128B rows, chunk^=(row&7)
  const int vsel = (((lane & 7) ^ ((lane >> 3) & 7)) << 4);
  const int vr = lane >> 3;                    // 0..7
  i32x4 cpv[4] = {};
  for (int cch = 0; cch < 8; cch++){
    const int n0 = cch * 128;
    __syncthreads();
    GLOAD16(&kbase[(size_t)(n0 + w*32 + kr)*DHEAD + ksel],      &Ks[w*32][0]);
    GLOAD16(&kbase[(size_t)(n0 + w*32 + 16 + kr)*DHEAD + ksel], &Ks[w*32 + 16][0]);
    GLOAD16(&vbase[(size_t)(w*16 + vr)*S_LEN + n0 + vsel],      &Vs[w*16][0]);
    GLOAD16(&vbase[(size_t)(w*16 + 8 + vr)*S_LEN + n0 + vsel],  &Vs[w*16 + 8][0]);
    __syncthreads();
#pragma unroll
    for (int nt = 0; nt < 8; nt++){
      int row = nt*16 + rr;
      i32x4 b = *(const i32x4*)((const i8*)Ks + row*64 + (((g ^ ((row >> 1) & 3))) << 4));
      i32x4 acc = {};
      acc = MFMAI8(b, a, acc);                       // SWAPPED: D[key][q]
      unsigned pw = 0;
#pragma unroll
      for (int r = 0; r < 4; r++){
        float e  = EXP2F(fmaf((float)acc[r], C1, nb));
        int   pq = (int)fminf(rintf(e), 255.0f);
        pw |= (unsigned)pq << (8*r);
      }
      pw ^= 0x80808080u;                             // -128 per byte
      *(unsigned*)&P[w][rr][nt*16 + g*4] = pw;
    }
    // PV: within-wave P dependency (lgkmcnt orders write->read; no barrier needed)
#pragma unroll
    for (int h = 0; h < 2; h++){
      i32x4 pa;
      {
        const i8* pptr = &P[w][rr][h*64 + g*16];
        pa[0] = *(const int*)(pptr + 0);
        pa[1] = *(const int*)(pptr + 4);
        pa[2] = *(const int*)(pptr + 8);
        pa[3] = *(const int*)(pptr + 12);
      }
#pragma unroll
      for (int f = 0; f < 4; f++){
        int row = f*16 + rr;
        i32x4 bv = *(const i32x4*)((const i8*)Vs + row*128 + (((h*4 + g) ^ (row & 7)) << 4));
        cpv[f] = MFMAI8(pa, bv, cpv[f]);
      }
    }
  }
  const int b = bhead >> 4, hh = bhead & 15;
  float lmax = 0.0f;
#pragma unroll
  for (int f = 0; f < 4; f++){
    int d = f*16 + rr;
    int vcorr = 128 * vtot[bhead*DHEAD + d];
#pragma unroll
    for (int r = 0; r < 4; r++){
      int srow2 = q0 + w*16 + g*4 + r;
      float y = fac * (float)(cpv[f][r] + vcorr);
      aout[(size_t)(srow2*BATCH + b)*EMB + hh*DHEAD + d] = y;
      lmax = fmaxf(lmax, fabsf(y));
    }
  }
  lmax = wave_max(lmax);
  __syncthreads();
  if (lane == 0) red[w] = lmax;
  __syncthreads();
  if (tid == 0){
    float mm = fmaxf(fmaxf(red[0], red[1]), fmaxf(red[2], red[3]));
    atomicMax(amax_out, __float_as_int(mm));
  }
}

extern "C" void kernel_launch(void* const* d_in, const int* in_sizes, int n_in,
                              void* d_out, int out_size, void* d_ws, size_t ws_size,
                              hipStream_t stream){
  const float* query = (const float*)d_in[0];
  const float* key   = (const float*)d_in[1];
  const float* value = (const float*)d_in[2];
  const float* inW   = (const float*)d_in[3];
  const float* inB   = (const float*)d_in[4];
  const float* outW  = (const float*)d_in[5];
  const float* outB  = (const float*)d_in[6];
  float* out = (float*)d_out;

  char* ws = (char*)d_ws;
  float* sc  = (float*)ws;
  int*   sci = (int*)ws;
  int*   vtotI = (int*)(ws + 256);               // 64x64 i32 = 16 KB
  u8* WQQ = (u8*)(ws + 256 + 16384);             // weights int8, 1MB each
  u8* WKQ = WQQ + 1024*1024;
  u8* WVQ = WKQ + 1024*1024;
  u8* WOQ = WVQ + 1024*1024;
  u8* XQ  = WOQ + 1024*1024;                     // acts int8, 4MB each
  u8* XK  = XQ + (size_t)NTOK*1024;
  u8* XV  = XK + (size_t)NTOK*1024;
  float* QF = (float*)(XV + (size_t)NTOK*1024);  // f32, 16MB each
  float* KF = QF + (size_t)NTOK*1024;
  float* VF = KF + (size_t)NTOK*1024;
  i8* VT = (i8*)(VF + (size_t)NTOK*1024);        // int8 V^T, 4MB
  float* MROW = (float*)(VT + (size_t)BHEAD*DHEAD*S_LEN);
  float* LROW = MROW + BHEAD*S_LEN;
  // reuse (lifetimes are disjoint along the serial stream):
  i8* QH  = (i8*)XQ;   i8* KH = (i8*)XK;         // proj-input quants dead after GEMMs
  float* AOUT = QF;                              // q f32 dead after k_quant_heads
  u8* AOQ = XV;                                  // v int8 input dead after gemm3

  AQTable tab;
  tab.d[0] = { query,             XQ,  NTOK*1024/4, 0, 128.f, -128.f };
  tab.d[1] = { key,               XK,  NTOK*1024/4, 1, 128.f, -128.f };
  tab.d[2] = { value,             XV,  NTOK*1024/4, 2, 128.f, -128.f };
  tab.d[3] = { inW,               WQQ, 1024*1024/4, 3, 127.f, -127.f };
  tab.d[4] = { inW + 1024*1024,   WKQ, 1024*1024/4, 4, 127.f, -127.f };
  tab.d[5] = { inW + 2*1024*1024, WVQ, 1024*1024/4, 5, 127.f, -127.f };
  tab.d[6] = { outW,              WOQ, 1024*1024/4, 6, 127.f, -127.f };

  k_zero<<<17, 256, 0, stream>>>(sc, vtotI);
  k_absmax7<<<2048, 256, 0, stream>>>(tab, sci);
  k_quant7<<<2048, 256, 0, stream>>>(tab, sc);
  k_gemm3<<<768, 512, 0, stream>>>((const i8*)XQ, (const i8*)WQQ, inB, QF, sc, sci);
  k_quant_heads<<<1024, 256, 0, stream>>>(QF, KF, VF, QH, KH, VT, vtotI, sc);
  k_attn1<<<1024, 256, 0, stream>>>(QH, KH, MROW, LROW, sc, sci);
  k_attn2<<<1024, 256, 0, stream>>>(QH, KH, VT, MROW, LROW, vtotI, AOUT, sc, sci, sci + 10);
  k_quant<<<1024, 256, 0, stream>>>(AOUT, AOQ, sc, 10);
  k_gemm1<<<256, 512, 0, stream>>>((const i8*)AOQ, (const i8*)WOQ, outB, out, sc, 10, 6, sci + 12);
}

// Round 17
// 177.830 us; speedup vs baseline: 1.1773x; 1.0063x over previous
//
#include <hip/hip_runtime.h>
#include <stdint.h>

typedef unsigned short u16;
typedef signed char i8;
typedef unsigned char u8;
typedef __attribute__((ext_vector_type(8))) short bf16x8;
typedef __attribute__((ext_vector_type(4))) float f32x4;
typedef __attribute__((ext_vector_type(4))) int i32x4;

#define S_LEN 1024
#define BATCH 4
#define EMB   1024
#define NH    16
#define DHEAD 64
#define BHEAD 64
#define NTOK  4096
#define KDIM  1024
#define NDIM  1024
#define EPSF  1e-8f
#define LOG2E 1.4426950408889634f

#define MFMAI8(a,b,c)  __builtin_amdgcn_mfma_i32_16x16x64_i8((a),(b),(c),0,0,0)

#define GLOAD16(g, l) __builtin_amdgcn_global_load_lds( \
    (const __attribute__((address_space(1))) void*)(g), \
    (__attribute__((address_space(3))) void*)(l), 16, 0, 0)

#define EXP2F(x) __builtin_amdgcn_exp2f(x)

__device__ __forceinline__ unsigned pack4(float a, float b, float c, float d){
  int qa = (int)a, qb = (int)b, qc = (int)c, qd = (int)d;
  return (unsigned)(qa & 255) | ((unsigned)(qb & 255) << 8) |
         ((unsigned)(qc & 255) << 16) | ((unsigned)(qd & 255) << 24);
}

__device__ __forceinline__ float wave_max(float v){
#pragma unroll
  for (int off = 32; off > 0; off >>= 1) v = fmaxf(v, __shfl_xor(v, off));
  return v;
}

// ---------------- scale slots ----------------
// 0 amax_query 1 amax_key 2 amax_value 3 amax_Wq 4 amax_Wk 5 amax_Wv 6 amax_Wo
// 7 amax_qproj 8 amax_kproj 9 amax_vproj 10 amax_attnout 11 unused 12 dummy 13 inv_l_max

// zero sc[0..15] and vtot[4096]
__global__ __launch_bounds__(256) void k_zero(float* sc, int* vtot){
  if (blockIdx.x == 0){
    if (threadIdx.x < 16) sc[threadIdx.x] = 0.0f;
  } else {
    vtot[(blockIdx.x - 1)*256 + threadIdx.x] = 0;
  }
}

struct AQDesc { const float* x; u8* y; int n4; int slot; float qdiv; float lo; };
struct AQTable { AQDesc d[7]; };

// merged absmax over 7 tensors; grid = 2048. Every segment is EXACTLY 8 iterations:
// q/k/v: 1M float4 / (512 blk * 256 thr) = 8; weights: 256K / (128*256) = 8.
__global__ __launch_bounds__(256) void k_absmax7(AQTable t, int* __restrict__ sci){
  const int bid = blockIdx.x;
  int seg, b0, nb;
  if (bid < 1536){ seg = bid >> 9; b0 = seg << 9; nb = 512; }
  else { seg = 3 + ((bid - 1536) >> 7); b0 = 1536 + ((seg - 3) << 7); nb = 128; }
  const AQDesc D = t.d[seg];
  const float4* x4 = (const float4*)D.x;
  const int base = (bid - b0)*256 + threadIdx.x;
  const int stride = nb*256;
  float4 v[8];
#pragma unroll
  for (int it = 0; it < 8; it++) v[it] = x4[base + it*stride];
  float m = 0.0f;
#pragma unroll
  for (int it = 0; it < 8; it++)
    m = fmaxf(m, fmaxf(fmaxf(fabsf(v[it].x), fabsf(v[it].y)),
                       fmaxf(fabsf(v[it].z), fabsf(v[it].w))));
  m = wave_max(m);
  __shared__ float red[4];
  int lane = threadIdx.x & 63, w = threadIdx.x >> 6;
  if (lane == 0) red[w] = m;
  __syncthreads();
  if (threadIdx.x == 0){
    float mm = fmaxf(fmaxf(red[0], red[1]), fmaxf(red[2], red[3]));
    atomicMax(sci + D.slot, __float_as_int(mm));
  }
}

// merged fake-quant of 7 tensors to int8 grid; same static 8-iteration structure
__global__ __launch_bounds__(256) void k_quant7(AQTable t, const float* __restrict__ sc){
  const int bid = blockIdx.x;
  int seg, b0, nb;
  if (bid < 1536){ seg = bid >> 9; b0 = seg << 9; nb = 512; }
  else { seg = 3 + ((bid - 1536) >> 7); b0 = 1536 + ((seg - 3) << 7); nb = 128; }
  const AQDesc D = t.d[seg];
  const float s = fmaxf(sc[D.slot] / D.qdiv, EPSF);
  const float lo = D.lo;
  const float4* x4 = (const float4*)D.x;
  unsigned* y4 = (unsigned*)D.y;
  const int base = (bid - b0)*256 + threadIdx.x;
  const int stride = nb*256;
  float4 v[8];
#pragma unroll
  for (int it = 0; it < 8; it++) v[it] = x4[base + it*stride];
#pragma unroll
  for (int it = 0; it < 8; it++){
    float t0 = fminf(fmaxf(rintf(v[it].x / s), lo), 127.f);
    float t1 = fminf(fmaxf(rintf(v[it].y / s), lo), 127.f);
    float t2 = fminf(fmaxf(rintf(v[it].z / s), lo), 127.f);
    float t3 = fminf(fmaxf(rintf(v[it].w / s), lo), 127.f);
    y4[base + it*stride] = pack4(t0, t1, t2, t3);
  }
}

// single-tensor quant to int8 (attention output); grid 1024 -> exactly 4 iterations
__global__ __launch_bounds__(256) void k_quant(const float* __restrict__ x,
    u8* __restrict__ y, const float* __restrict__ sc, int slot){
  const float s = fmaxf(sc[slot] / 128.0f, EPSF);
  const float4* x4 = (const float4*)x;
  unsigned* y4 = (unsigned*)y;
  const int base = blockIdx.x*256 + threadIdx.x;
  const int stride = 1024*256;
  float4 v[4];
#pragma unroll
  for (int it = 0; it < 4; it++) v[it] = x4[base + it*stride];
#pragma unroll
  for (int it = 0; it < 4; it++){
    float t0 = fminf(fmaxf(rintf(v[it].x / s), -128.f), 127.f);
    float t1 = fminf(fmaxf(rintf(v[it].y / s), -128.f), 127.f);
    float t2 = fminf(fmaxf(rintf(v[it].z / s), -128.f), 127.f);
    float t3 = fminf(fmaxf(rintf(v[it].w / s), -128.f), 127.f);
    y4[base + it*stride] = pack4(t0, t1, t2, t3);
  }
}

// ---------------- GEMM: 128x128 tile, BK=128 int8, 8 waves, 2-barrier + swizzle ----
__device__ __forceinline__ void gemm_body(const i8* __restrict__ A,
    const i8* __restrict__ W, const float* __restrict__ bias,
    float* __restrict__ out, float s_b, int rowBase, int colBase,
    int* __restrict__ amax_out, i8 (*As)[128], i8 (*Bs)[128], float* red){
  const int tid = threadIdx.x;
  const int wid = tid >> 6, lane = tid & 63;
  const int wm = wid >> 2, wn = wid & 3;
  const int rr = lane & 15, g = lane >> 4;
  const int srow = wid*8 + (lane >> 3);
  const int sco  = ((lane & 7) ^ (lane >> 3)) << 4;
  const i8* Arow0 = &A[(size_t)(rowBase + srow)*KDIM + sco];
  const i8* Arow1 = &A[(size_t)(rowBase + 64 + srow)*KDIM + sco];
  const i8* Wrow0 = &W[(size_t)(colBase + srow)*KDIM + sco];
  const i8* Wrow1 = &W[(size_t)(colBase + 64 + srow)*KDIM + sco];
  i32x4 c[4][2] = {};
  int aoff[4][2], boff[2][2];
#pragma unroll
  for (int i = 0; i < 4; i++){
    int row = wm*64 + i*16 + rr;
#pragma unroll
    for (int h = 0; h < 2; h++)
      aoff[i][h] = row*128 + (((h*4 + g) ^ (row & 7)) << 4);
  }
#pragma unroll
  for (int j = 0; j < 2; j++){
    int row = wn*32 + j*16 + rr;
#pragma unroll
    for (int h = 0; h < 2; h++)
      boff[j][h] = row*128 + (((h*4 + g) ^ (row & 7)) << 4);
  }
  for (int k0 = 0; k0 < KDIM; k0 += 128){
    __syncthreads();
    GLOAD16(Arow0 + k0, &As[wid*8][0]);
    GLOAD16(Arow1 + k0, &As[64 + wid*8][0]);
    GLOAD16(Wrow0 + k0, &Bs[wid*8][0]);
    GLOAD16(Wrow1 + k0, &Bs[64 + wid*8][0]);
    __syncthreads();
#pragma unroll
    for (int h = 0; h < 2; h++){
      i32x4 af[4], bfr[2];
#pragma unroll
      for (int i = 0; i < 4; i++) af[i]  = *(const i32x4*)((const i8*)As + aoff[i][h]);
#pragma unroll
      for (int j = 0; j < 2; j++) bfr[j] = *(const i32x4*)((const i8*)Bs + boff[j][h]);
#pragma unroll
      for (int i = 0; i < 4; i++)
#pragma unroll
        for (int j = 0; j < 2; j++)
          c[i][j] = MFMAI8(af[i], bfr[j], c[i][j]);
    }
  }
  float lmax = 0.0f;
  const int r0 = (lane >> 4) * 4, ccol = lane & 15;
#pragma unroll
  for (int j = 0; j < 2; j++){
    int col = colBase + wn*32 + j*16 + ccol;
    float rb = rintf(bias[col] / s_b);
#pragma unroll
    for (int i = 0; i < 4; i++){
      int rowb = rowBase + wm*64 + i*16 + r0;
#pragma unroll
      for (int rI = 0; rI < 4; rI++){
        float y = s_b * ((float)c[i][j][rI] + rb);
        out[(size_t)(rowb + rI)*NDIM + col] = y;
        lmax = fmaxf(lmax, fabsf(y));
      }
    }
  }
  lmax = wave_max(lmax);
  if (lane == 0) red[wid] = lmax;
  __syncthreads();
  if (tid == 0){
    float mm = red[0];
#pragma unroll
    for (int i2 = 1; i2 < 8; i2++) mm = fmaxf(mm, red[i2]);
    atomicMax(amax_out, __float_as_int(mm));
  }
}

// QKV projections fused: grid 768 (3 segs x 256 tiles), XCD-chunked swizzle
__global__ __launch_bounds__(512) void k_gemm3(const i8* __restrict__ Xall,
    const i8* __restrict__ Wall, const float* __restrict__ ball,
    float* __restrict__ Yall, const float* __restrict__ sc, int* __restrict__ sci){
  __shared__ i8 As[128][128];
  __shared__ i8 Bs[128][128];
  __shared__ float red[8];
  const int orig = blockIdx.x;
  const int xcd = orig & 7, sl = orig >> 3;
  const int seg = sl >> 5;
  const int t2 = xcd*32 + (sl & 31);
  const int by = t2 >> 3, bx = t2 & 7;
  const float s_x = fmaxf(sc[seg] / 128.0f, EPSF);
  const float s_w = fmaxf(sc[3 + seg] / 127.0f, EPSF);
  gemm_body(Xall + (size_t)seg*NTOK*KDIM, Wall + (size_t)seg*KDIM*NDIM,
            ball + seg*1024, Yall + (size_t)seg*NTOK*NDIM, s_x*s_w,
            by*128, bx*128, sci + 7 + seg, As, Bs, red);
}

// out-projection: grid 256
__global__ __launch_bounds__(512) void k_gemm1(const i8* __restrict__ A,
    const i8* __restrict__ W, const float* __restrict__ bias,
    float* __restrict__ out, const float* __restrict__ sc,
    int sx_slot, int sw_slot, int* __restrict__ amax_out){
  __shared__ i8 As[128][128];
  __shared__ i8 Bs[128][128];
  __shared__ float red[8];
  const int orig = blockIdx.x;
  const int t2 = (orig & 7)*32 + (orig >> 3);
  const int by = t2 >> 3, bx = t2 & 7;
  const float s_x = fmaxf(sc[sx_slot] / 128.0f, EPSF);
  const float s_w = fmaxf(sc[sw_slot] / 127.0f, EPSF);
  gemm_body(A, W, bias, out, s_x*s_w, by*128, bx*128, amax_out, As, Bs, red);
}

// q/k/v f32 (S,B,E) -> qh,kh int8 [BH][S][DH]; vt int8 [BH][DH][S]; vtot[bh][d] = sum_key v
__global__ __launch_bounds__(256) void k_quant_heads(const float* __restrict__ qf,
    const float* __restrict__ kf, const float* __restrict__ vf,
    i8* __restrict__ qh, i8* __restrict__ kh, i8* __restrict__ vt,
    int* __restrict__ vtot, const float* __restrict__ sc){
  const float s_q = fmaxf((sc[7]*0.125f)/128.0f, EPSF);  // scale of q/sqrt(64)
  const float s_k = fmaxf(sc[8]/128.0f, EPSF);
  const float s_v = fmaxf(sc[9]/128.0f, EPSF);
  __shared__ i8 tile[64][68];
  const int bx = blockIdx.x;
  const int st = bx & 15, hh = (bx >> 4) & 15, b = bx >> 8;
  const int t = threadIdx.x;
  const int sl = t >> 2, dc = (t & 3) * 16;
  const size_t row = (size_t)(st*64 + sl)*BATCH + b;
  const size_t ibase = row*EMB + hh*DHEAD + dc;
  const int bh = b*NH + hh;
  float vq[16], vk[16], vv[16];
#pragma unroll
  for (int i = 0; i < 4; i++){
    *(float4*)&vq[i*4] = *(const float4*)&qf[ibase + i*4];
    *(float4*)&vk[i*4] = *(const float4*)&kf[ibase + i*4];
    *(float4*)&vv[i*4] = *(const float4*)&vf[ibase + i*4];
  }
  alignas(16) i8 oq[16], ok[16];
#pragma unroll
  for (int i = 0; i < 16; i++){
    float tq = fminf(fmaxf(rintf((vq[i]*0.125f)/s_q), -128.f), 127.f);
    float tk = fminf(fmaxf(rintf(vk[i]/s_k), -128.f), 127.f);
    float tv = fminf(fmaxf(rintf(vv[i]/s_v), -128.f), 127.f);
    oq[i] = (i8)(int)tq; ok[i] = (i8)(int)tk;
    tile[dc + i][sl] = (i8)(int)tv;
  }
  const size_t qoff = ((size_t)bh*S_LEN + st*64 + sl)*DHEAD + dc;
  *(int4*)&qh[qoff] = *(const int4*)&oq[0];
  *(int4*)&kh[qoff] = *(const int4*)&ok[0];
  __syncthreads();
  const int d = t >> 2, sc4 = (t & 3) * 16;
  int ovi[4];
  int sum = 0;
#pragma unroll
  for (int w4 = 0; w4 < 4; w4++){
    unsigned x = *(const unsigned*)&tile[d][sc4 + w4*4];
    ovi[w4] = (int)x;
#pragma unroll
    for (int bb = 0; bb < 4; bb++) sum += (int)(i8)(x >> (8*bb));
  }
  const size_t voff = ((size_t)bh*DHEAD + d)*S_LEN + st*64 + sc4;
  *(int4*)&vt[voff] = *(const int4*)&ovi[0];
  sum += __shfl_xor(sum, 1);
  sum += __shfl_xor(sum, 2);
  if ((t & 3) == 0) atomicAdd(&vtot[bh*DHEAD + d], sum);
}

// attention pass 1: KVBLK=128, 4 waves / 64 q-rows, grid 1024. SWAPPED int8 QK^T,
// online (m,l) in log2 domain; per-lane scalars.
__global__ __launch_bounds__(256) void k_attn1(const i8* __restrict__ qh,
    const i8* __restrict__ kh, float* __restrict__ mrow, float* __restrict__ lrow,
    const float* __restrict__ sc, int* __restrict__ sci){
  __shared__ i8 Ks[128][64];
  __shared__ float red2[4];
  const int orig = blockIdx.x;
  const int tile = (orig & 7) * 128 + (orig >> 3);   // XCD-chunked swizzle
  const int bhead = tile >> 4, q0 = (tile & 15) * 64;
  const int tid = threadIdx.x, w = tid >> 6, lane = tid & 63;
  const int rr = lane & 15, g = lane >> 4;
  const float s_q = fmaxf((sc[7]*0.125f)/128.0f, EPSF);
  const float s_k = fmaxf(sc[8]/128.0f, EPSF);
  const float C1 = s_q * s_k * LOG2E;                // scores scaled to log2 domain
  const i8* qbase = qh + ((size_t)bhead*S_LEN + q0 + w*16)*DHEAD;
  const i8* kbase = kh + (size_t)bhead*S_LEN*DHEAD;
  i32x4 a = *(const i32x4*)&qbase[rr*DHEAD + g*16];  // Q fragment (B operand)
  // staging: wave w stages Ks rows w*32..w*32+31 (2 gloads of 16 rows)
  const int ksel = ((lane & 3) ^ ((lane >> 3) & 3)) << 4;   // lane-only source sel
  const int kr = lane >> 2;                                  // 0..15
  float m = -1e30f, l = 0.0f;
  for (int cch = 0; cch < 8; cch++){
    const int n0 = cch * 128;
    __syncthreads();
    GLOAD16(&kbase[(size_t)(n0 + w*32 + kr)*DHEAD + ksel],      &Ks[w*32][0]);
    GLOAD16(&kbase[(size_t)(n0 + w*32 + 16 + kr)*DHEAD + ksel], &Ks[w*32 + 16][0]);
    __syncthreads();
    float sv[8][4];
#pragma unroll
    for (int nt = 0; nt < 8; nt++){
      int row = nt*16 + rr;
      i32x4 b = *(const i32x4*)((const i8*)Ks + row*64 + (((g ^ ((row >> 1) & 3))) << 4));
      i32x4 acc = {};
      acc = MFMAI8(b, a, acc);                       // SWAPPED: D[key][q]
#pragma unroll
      for (int r = 0; r < 4; r++) sv[nt][r] = (float)acc[r]*C1;
    }
    float cm = sv[0][0];
#pragma unroll
    for (int nt = 0; nt < 8; nt++)
#pragma unroll
      for (int r = 0; r < 4; r++) cm = fmaxf(cm, sv[nt][r]);
    float mn = fmaxf(m, cm);
    l *= EXP2F(m - mn);                              // 1.0 when max unchanged
    m = mn;
#pragma unroll
    for (int nt = 0; nt < 8; nt++)
#pragma unroll
      for (int r = 0; r < 4; r++) l += EXP2F(sv[nt][r] - m);
  }
  // merge (m,l) across the 4 g-lanes sharing q-row rr
#pragma unroll
  for (int off = 16; off < 64; off <<= 1){
    float mo = __shfl_xor(m, off), lo = __shfl_xor(l, off);
    float mn = fmaxf(m, mo);
    l = l*EXP2F(m - mn) + lo*EXP2F(mo - mn);
    m = mn;
  }
  if (g == 0){
    mrow[(size_t)bhead*S_LEN + q0 + w*16 + rr] = m;  // log2-domain max
    lrow[(size_t)bhead*S_LEN + q0 + w*16 + rr] = l;
  }
  float im = wave_max(1.0f / l);
  if (lane == 0) red2[w] = im;
  __syncthreads();
  if (tid == 0){
    float mm = fmaxf(fmaxf(red2[0], red2[1]), fmaxf(red2[2], red2[3]));
    atomicMax(sci + 13, __float_as_int(mm));
  }
}

// attention pass 2: KVBLK=128. SWAPPED int8 QK^T + int8 PV with -128 offset.
// P-pack via v_cvt_pk_u8_f32; input pre-rounded AND pre-clamped to [0,255] so the
// pack is exact regardless of the instruction's rounding mode.
__global__ __launch_bounds__(256) void k_attn2(const i8* __restrict__ qh,
    const i8* __restrict__ kh, const i8* __restrict__ vt,
    const float* __restrict__ mrow, const float* __restrict__ lrow,
    const int* __restrict__ vtot, float* __restrict__ aout,
    const float* __restrict__ sc, const int* __restrict__ sci,
    int* __restrict__ amax_out){
  __shared__ i8 Ks[128][64];
  __shared__ i8 Vs[64][128];
  __shared__ i8 P[4][16][136];
  __shared__ float red[4];
  const int orig = blockIdx.x;
  const int tile = (orig & 7) * 128 + (orig >> 3);   // XCD-chunked swizzle
  const int bhead = tile >> 4, q0 = (tile & 15) * 64;
  const int tid = threadIdx.x, w = tid >> 6, lane = tid & 63;
  const int rr = lane & 15, g = lane >> 4;
  const float s_q = fmaxf((sc[7]*0.125f)/128.0f, EPSF);
  const float s_k = fmaxf(sc[8]/128.0f, EPSF);
  const float C1 = s_q * s_k * LOG2E;
  const float s_v = fmaxf(sc[9]/128.0f, EPSF);
  const float s_a = fmaxf(__int_as_float(sci[13]) / 255.0f, EPSF);
  const float fac = s_a * s_v;
  const i8* qbase = qh + ((size_t)bhead*S_LEN + q0 + w*16)*DHEAD;
  const i8* kbase = kh + (size_t)bhead*S_LEN*DHEAD;
  const i8* vbase = vt + (size_t)bhead*DHEAD*S_LEN;
  i32x4 a = *(const i32x4*)&qbase[rr*DHEAD + g*16];  // Q fragment (B operand)
  // per-lane scalars for q-row rr: nb = log2(inv) - m  (inv folded into exponent)
  float nb;
  {
    size_t qr = (size_t)bhead*S_LEN + q0 + w*16 + rr;
    float inv = 1.0f / (lrow[qr] * s_a);
    nb = log2f(inv) - mrow[qr];
  }
  // K staging: wave w stages rows w*32..w*32+31; lane-only selector
  const int ksel = ((lane & 3) ^ ((lane >> 3) & 3)) << 4;
  const int kr = lane >> 2;                    // 0..15
  // V staging: wave w stages d-rows w*16..w*16+15; 128B rows, chunk^=(row&7)
  const int vsel = (((lane & 7) ^ ((lane >> 3) & 7)) << 4);
  const int vr = lane >> 3;                    // 0..7
  i32x4 cpv[4] = {};
  for (int cch = 0; cch < 8; cch++){
    const int n0 = cch * 128;
    __syncthreads();
    GLOAD16(&kbase[(size_t)(n0 + w*32 + kr)*DHEAD + ksel],      &Ks[w*32][0]);
    GLOAD16(&kbase[(size_t)(n0 + w*32 + 16 + kr)*DHEAD + ksel], &Ks[w*32 + 16][0]);
    GLOAD16(&vbase[(size_t)(w*16 + vr)*S_LEN + n0 + vsel],      &Vs[w*16][0]);
    GLOAD16(&vbase[(size_t)(w*16 + 8 + vr)*S_LEN + n0 + vsel],  &Vs[w*16 + 8][0]);
    __syncthreads();
#pragma unroll
    for (int nt = 0; nt < 8; nt++){
      int row = nt*16 + rr;
      i32x4 b = *(const i32x4*)((const i8*)Ks + row*64 + (((g ^ ((row >> 1) & 3))) << 4));
      i32x4 acc = {};
      acc = MFMAI8(b, a, acc);                       // SWAPPED: D[key][q]
      float er0 = fminf(rintf(EXP2F(fmaf((float)acc[0], C1, nb))), 255.0f);
      float er1 = fminf(rintf(EXP2F(fmaf((float)acc[1], C1, nb))), 255.0f);
      float er2 = fminf(rintf(EXP2F(fmaf((float)acc[2], C1, nb))), 255.0f);
      float er3 = fminf(rintf(EXP2F(fmaf((float)acc[3], C1, nb))), 255.0f);
      unsigned pw;
      asm("v_cvt_pk_u8_f32 %0, %1, 0, 0"  : "=v"(pw) : "v"(er0));
      asm("v_cvt_pk_u8_f32 %0, %1, 1, %0" : "+v"(pw) : "v"(er1));
      asm("v_cvt_pk_u8_f32 %0, %1, 2, %0" : "+v"(pw) : "v"(er2));
      asm("v_cvt_pk_u8_f32 %0, %1, 3, %0" : "+v"(pw) : "v"(er3));
      pw ^= 0x80808080u;                             // -128 per byte
      *(unsigned*)&P[w][rr][nt*16 + g*4] = pw;
    }
    // PV: within-wave P dependency (lgkmcnt orders write->read; no barrier needed)
#pragma unroll
    for (int h = 0; h < 2; h++){
      i32x4 pa;
      {
        const i8* pptr = &P[w][rr][h*64 + g*16];
        pa[0] = *(const int*)(pptr + 0);
        pa[1] = *(const int*)(pptr + 4);
        pa[2] = *(const int*)(pptr + 8);
        pa[3] = *(const int*)(pptr + 12);
      }
#pragma unroll
      for (int f = 0; f < 4; f++){
        int row = f*16 + rr;
        i32x4 bv = *(const i32x4*)((const i8*)Vs + row*128 + (((h*4 + g) ^ (row & 7)) << 4));
        cpv[f] = MFMAI8(pa, bv, cpv[f]);
      }
    }
  }
  const int b = bhead >> 4, hh = bhead & 15;
  float lmax = 0.0f;
#pragma unroll
  for (int f = 0; f < 4; f++){
    int d = f*16 + rr;
    int vcorr = 128 * vtot[bhead*DHEAD + d];
#pragma unroll
    for (int r = 0; r < 4; r++){
      int srow2 = q0 + w*16 + g*4 + r;
      float y = fac * (float)(cpv[f][r] + vcorr);
      aout[(size_t)(srow2*BATCH + b)*EMB + hh*DHEAD + d] = y;
      lmax = fmaxf(lmax, fabsf(y));
    }
  }
  lmax = wave_max(lmax);
  __syncthreads();
  if (lane == 0) red[w] = lmax;
  __syncthreads();
  if (tid == 0){
    float mm = fmaxf(fmaxf(red[0], red[1]), fmaxf(red[2], red[3]));
    atomicMax(amax_out, __float_as_int(mm));
  }
}

extern "C" void kernel_launch(void* const* d_in, const int* in_sizes, int n_in,
                              void* d_out, int out_size, void* d_ws, size_t ws_size,
                              hipStream_t stream){
  const float* query = (const float*)d_in[0];
  const float* key   = (const float*)d_in[1];
  const float* value = (const float*)d_in[2];
  const float* inW   = (const float*)d_in[3];
  const float* inB   = (const float*)d_in[4];
  const float* outW  = (const float*)d_in[5];
  const float* outB  = (const float*)d_in[6];
  float* out = (float*)d_out;

  char* ws = (char*)d_ws;
  float* sc  = (float*)ws;
  int*   sci = (int*)ws;
  int*   vtotI = (int*)(ws + 256);               // 64x64 i32 = 16 KB
  u8* WQQ = (u8*)(ws + 256 + 16384);             // weights int8, 1MB each
  u8* WKQ = WQQ + 1024*1024;
  u8* WVQ = WKQ + 1024*1024;
  u8* WOQ = WVQ + 1024*1024;
  u8* XQ  = WOQ + 1024*1024;                     // acts int8, 4MB each
  u8* XK  = XQ + (size_t)NTOK*1024;
  u8* XV  = XK + (size_t)NTOK*1024;
  float* QF = (float*)(XV + (size_t)NTOK*1024);  // f32, 16MB each
  float* KF = QF + (size_t)NTOK*1024;
  float* VF = KF + (size_t)NTOK*1024;
  i8* VT = (i8*)(VF + (size_t)NTOK*1024);        // int8 V^T, 4MB
  float* MROW = (float*)(VT + (size_t)BHEAD*DHEAD*S_LEN);
  float* LROW = MROW + BHEAD*S_LEN;
  // reuse (lifetimes are disjoint along the serial stream):
  i8* QH  = (i8*)XQ;   i8* KH = (i8*)XK;         // proj-input quants dead after GEMMs
  float* AOUT = QF;                              // q f32 dead after k_quant_heads
  u8* AOQ = XV;                                  // v int8 input dead after gemm3

  AQTable tab;
  tab.d[0] = { query,             XQ,  NTOK*1024/4, 0, 128.f, -128.f };
  tab.d[1] = { key,               XK,  NTOK*1024/4, 1, 128.f, -128.f };
  tab.d[2] = { value,             XV,  NTOK*1024/4, 2, 128.f, -128.f };
  tab.d[3] = { inW,               WQQ, 1024*1024/4, 3, 127.f, -127.f };
  tab.d[4] = { inW + 1024*1024,   WKQ, 1024*1024/4, 4, 127.f, -127.f };
  tab.d[5] = { inW + 2*1024*1024, WVQ, 1024*1024/4, 5, 127.f, -127.f };
  tab.d[6] = { outW,              WOQ, 1024*1024/4, 6, 127.f, -127.f };

  k_zero<<<17, 256, 0, stream>>>(sc, vtotI);
  k_absmax7<<<2048, 256, 0, stream>>>(tab, sci);
  k_quant7<<<2048, 256, 0, stream>>>(tab, sc);
  k_gemm3<<<768, 512, 0, stream>>>((const i8*)XQ, (const i8*)WQQ, inB, QF, sc, sci);
  k_quant_heads<<<1024, 256, 0, stream>>>(QF, KF, VF, QH, KH, VT, vtotI, sc);
  k_attn1<<<1024, 256, 0, stream>>>(QH, KH, MROW, LROW, sc, sci);
  k_attn2<<<1024, 256, 0, stream>>>(QH, KH, VT, MROW, LROW, vtotI, AOUT, sc, sci, sci + 10);
  k_quant<<<1024, 256, 0, stream>>>(AOUT, AOQ, sc, 10);
  k_gemm1<<<256, 512, 0, stream>>>((const i8*)AOQ, (const i8*)WOQ, outB, out, sc, 10, 6, sci + 12);
}

// Round 18
// 172.968 us; speedup vs baseline: 1.2104x; 1.0281x over previous
//
#include <hip/hip_runtime.h>
#include <stdint.h>

typedef unsigned short u16;
typedef signed char i8;
typedef unsigned char u8;
typedef __attribute__((ext_vector_type(8))) short bf16x8;
typedef __attribute__((ext_vector_type(4))) float f32x4;
typedef __attribute__((ext_vector_type(4))) int i32x4;

#define S_LEN 1024
#define BATCH 4
#define EMB   1024
#define NH    16
#define DHEAD 64
#define BHEAD 64
#define NTOK  4096
#define KDIM  1024
#define NDIM  1024
#define EPSF  1e-8f
#define LOG2E 1.4426950408889634f

#define MFMAI8(a,b,c)  __builtin_amdgcn_mfma_i32_16x16x64_i8((a),(b),(c),0,0,0)

#define GLOAD16(g, l) __builtin_amdgcn_global_load_lds( \
    (const __attribute__((address_space(1))) void*)(g), \
    (__attribute__((address_space(3))) void*)(l), 16, 0, 0)

#define EXP2F(x) __builtin_amdgcn_exp2f(x)

__device__ __forceinline__ unsigned pack4(float a, float b, float c, float d){
  int qa = (int)a, qb = (int)b, qc = (int)c, qd = (int)d;
  return (unsigned)(qa & 255) | ((unsigned)(qb & 255) << 8) |
         ((unsigned)(qc & 255) << 16) | ((unsigned)(qd & 255) << 24);
}

__device__ __forceinline__ float wave_max(float v){
#pragma unroll
  for (int off = 32; off > 0; off >>= 1) v = fmaxf(v, __shfl_xor(v, off));
  return v;
}

// ---------------- scale slots ----------------
// 0 amax_query 1 amax_key 2 amax_value 3 amax_Wq 4 amax_Wk 5 amax_Wv 6 amax_Wo
// 7 amax_qproj 8 amax_kproj 9 amax_vproj 10 amax_attnout 11 unused 12 dummy 13 inv_l_max

// zero sc[0..15] and vtot[4096]
__global__ __launch_bounds__(256) void k_zero(float* sc, int* vtot){
  if (blockIdx.x == 0){
    if (threadIdx.x < 16) sc[threadIdx.x] = 0.0f;
  } else {
    vtot[(blockIdx.x - 1)*256 + threadIdx.x] = 0;
  }
}

struct AQDesc { const float* x; u8* y; int n4; int slot; float qdiv; float lo; };
struct AQTable { AQDesc d[7]; };

// merged absmax over 7 tensors; grid = 2048. Every segment is EXACTLY 8 iterations.
__global__ __launch_bounds__(256) void k_absmax7(AQTable t, int* __restrict__ sci){
  const int bid = blockIdx.x;
  int seg, b0, nb;
  if (bid < 1536){ seg = bid >> 9; b0 = seg << 9; nb = 512; }
  else { seg = 3 + ((bid - 1536) >> 7); b0 = 1536 + ((seg - 3) << 7); nb = 128; }
  const AQDesc D = t.d[seg];
  const float4* x4 = (const float4*)D.x;
  const int base = (bid - b0)*256 + threadIdx.x;
  const int stride = nb*256;
  float4 v[8];
#pragma unroll
  for (int it = 0; it < 8; it++) v[it] = x4[base + it*stride];
  float m = 0.0f;
#pragma unroll
  for (int it = 0; it < 8; it++)
    m = fmaxf(m, fmaxf(fmaxf(fabsf(v[it].x), fabsf(v[it].y)),
                       fmaxf(fabsf(v[it].z), fabsf(v[it].w))));
  m = wave_max(m);
  __shared__ float red[4];
  int lane = threadIdx.x & 63, w = threadIdx.x >> 6;
  if (lane == 0) red[w] = m;
  __syncthreads();
  if (threadIdx.x == 0){
    float mm = fmaxf(fmaxf(red[0], red[1]), fmaxf(red[2], red[3]));
    atomicMax(sci + D.slot, __float_as_int(mm));
  }
}

// merged fake-quant of 7 tensors to int8 grid; same static 8-iteration structure
__global__ __launch_bounds__(256) void k_quant7(AQTable t, const float* __restrict__ sc){
  const int bid = blockIdx.x;
  int seg, b0, nb;
  if (bid < 1536){ seg = bid >> 9; b0 = seg << 9; nb = 512; }
  else { seg = 3 + ((bid - 1536) >> 7); b0 = 1536 + ((seg - 3) << 7); nb = 128; }
  const AQDesc D = t.d[seg];
  const float s = fmaxf(sc[D.slot] / D.qdiv, EPSF);
  const float lo = D.lo;
  const float4* x4 = (const float4*)D.x;
  unsigned* y4 = (unsigned*)D.y;
  const int base = (bid - b0)*256 + threadIdx.x;
  const int stride = nb*256;
  float4 v[8];
#pragma unroll
  for (int it = 0; it < 8; it++) v[it] = x4[base + it*stride];
#pragma unroll
  for (int it = 0; it < 8; it++){
    float t0 = fminf(fmaxf(rintf(v[it].x / s), lo), 127.f);
    float t1 = fminf(fmaxf(rintf(v[it].y / s), lo), 127.f);
    float t2 = fminf(fmaxf(rintf(v[it].z / s), lo), 127.f);
    float t3 = fminf(fmaxf(rintf(v[it].w / s), lo), 127.f);
    y4[base + it*stride] = pack4(t0, t1, t2, t3);
  }
}

// single-tensor quant to int8 (attention output); grid 1024 -> exactly 4 iterations
__global__ __launch_bounds__(256) void k_quant(const float* __restrict__ x,
    u8* __restrict__ y, const float* __restrict__ sc, int slot){
  const float s = fmaxf(sc[slot] / 128.0f, EPSF);
  const float4* x4 = (const float4*)x;
  unsigned* y4 = (unsigned*)y;
  const int base = blockIdx.x*256 + threadIdx.x;
  const int stride = 1024*256;
  float4 v[4];
#pragma unroll
  for (int it = 0; it < 4; it++) v[it] = x4[base + it*stride];
#pragma unroll
  for (int it = 0; it < 4; it++){
    float t0 = fminf(fmaxf(rintf(v[it].x / s), -128.f), 127.f);
    float t1 = fminf(fmaxf(rintf(v[it].y / s), -128.f), 127.f);
    float t2 = fminf(fmaxf(rintf(v[it].z / s), -128.f), 127.f);
    float t3 = fminf(fmaxf(rintf(v[it].w / s), -128.f), 127.f);
    y4[base + it*stride] = pack4(t0, t1, t2, t3);
  }
}

// ---------------- GEMM: 128x128 tile, BK=128 int8, 8 waves, 2-barrier + swizzle ----
__device__ __forceinline__ void gemm_body(const i8* __restrict__ A,
    const i8* __restrict__ W, const float* __restrict__ bias,
    float* __restrict__ out, float s_b, int rowBase, int colBase,
    int* __restrict__ amax_out, i8 (*As)[128], i8 (*Bs)[128], float* red){
  const int tid = threadIdx.x;
  const int wid = tid >> 6, lane = tid & 63;
  const int wm = wid >> 2, wn = wid & 3;
  const int rr = lane & 15, g = lane >> 4;
  const int srow = wid*8 + (lane >> 3);
  const int sco  = ((lane & 7) ^ (lane >> 3)) << 4;
  const i8* Arow0 = &A[(size_t)(rowBase + srow)*KDIM + sco];
  const i8* Arow1 = &A[(size_t)(rowBase + 64 + srow)*KDIM + sco];
  const i8* Wrow0 = &W[(size_t)(colBase + srow)*KDIM + sco];
  const i8* Wrow1 = &W[(size_t)(colBase + 64 + srow)*KDIM + sco];
  i32x4 c[4][2] = {};
  int aoff[4][2], boff[2][2];
#pragma unroll
  for (int i = 0; i < 4; i++){
    int row = wm*64 + i*16 + rr;
#pragma unroll
    for (int h = 0; h < 2; h++)
      aoff[i][h] = row*128 + (((h*4 + g) ^ (row & 7)) << 4);
  }
#pragma unroll
  for (int j = 0; j < 2; j++){
    int row = wn*32 + j*16 + rr;
#pragma unroll
    for (int h = 0; h < 2; h++)
      boff[j][h] = row*128 + (((h*4 + g) ^ (row & 7)) << 4);
  }
  for (int k0 = 0; k0 < KDIM; k0 += 128){
    __syncthreads();
    GLOAD16(Arow0 + k0, &As[wid*8][0]);
    GLOAD16(Arow1 + k0, &As[64 + wid*8][0]);
    GLOAD16(Wrow0 + k0, &Bs[wid*8][0]);
    GLOAD16(Wrow1 + k0, &Bs[64 + wid*8][0]);
    __syncthreads();
#pragma unroll
    for (int h = 0; h < 2; h++){
      i32x4 af[4], bfr[2];
#pragma unroll
      for (int i = 0; i < 4; i++) af[i]  = *(const i32x4*)((const i8*)As + aoff[i][h]);
#pragma unroll
      for (int j = 0; j < 2; j++) bfr[j] = *(const i32x4*)((const i8*)Bs + boff[j][h]);
#pragma unroll
      for (int i = 0; i < 4; i++)
#pragma unroll
        for (int j = 0; j < 2; j++)
          c[i][j] = MFMAI8(af[i], bfr[j], c[i][j]);
    }
  }
  float lmax = 0.0f;
  const int r0 = (lane >> 4) * 4, ccol = lane & 15;
#pragma unroll
  for (int j = 0; j < 2; j++){
    int col = colBase + wn*32 + j*16 + ccol;
    float rb = rintf(bias[col] / s_b);
#pragma unroll
    for (int i = 0; i < 4; i++){
      int rowb = rowBase + wm*64 + i*16 + r0;
#pragma unroll
      for (int rI = 0; rI < 4; rI++){
        float y = s_b * ((float)c[i][j][rI] + rb);
        out[(size_t)(rowb + rI)*NDIM + col] = y;
        lmax = fmaxf(lmax, fabsf(y));
      }
    }
  }
  lmax = wave_max(lmax);
  if (lane == 0) red[wid] = lmax;
  __syncthreads();
  if (tid == 0){
    float mm = red[0];
#pragma unroll
    for (int i2 = 1; i2 < 8; i2++) mm = fmaxf(mm, red[i2]);
    atomicMax(amax_out, __float_as_int(mm));
  }
}

// QKV projections fused: grid 768 (3 segs x 256 tiles), XCD-chunked swizzle
__global__ __launch_bounds__(512) void k_gemm3(const i8* __restrict__ Xall,
    const i8* __restrict__ Wall, const float* __restrict__ ball,
    float* __restrict__ Yall, const float* __restrict__ sc, int* __restrict__ sci){
  __shared__ i8 As[128][128];
  __shared__ i8 Bs[128][128];
  __shared__ float red[8];
  const int orig = blockIdx.x;
  const int xcd = orig & 7, sl = orig >> 3;
  const int seg = sl >> 5;
  const int t2 = xcd*32 + (sl & 31);
  const int by = t2 >> 3, bx = t2 & 7;
  const float s_x = fmaxf(sc[seg] / 128.0f, EPSF);
  const float s_w = fmaxf(sc[3 + seg] / 127.0f, EPSF);
  gemm_body(Xall + (size_t)seg*NTOK*KDIM, Wall + (size_t)seg*KDIM*NDIM,
            ball + seg*1024, Yall + (size_t)seg*NTOK*NDIM, s_x*s_w,
            by*128, bx*128, sci + 7 + seg, As, Bs, red);
}

// out-projection: grid 256
__global__ __launch_bounds__(512) void k_gemm1(const i8* __restrict__ A,
    const i8* __restrict__ W, const float* __restrict__ bias,
    float* __restrict__ out, const float* __restrict__ sc,
    int sx_slot, int sw_slot, int* __restrict__ amax_out){
  __shared__ i8 As[128][128];
  __shared__ i8 Bs[128][128];
  __shared__ float red[8];
  const int orig = blockIdx.x;
  const int t2 = (orig & 7)*32 + (orig >> 3);
  const int by = t2 >> 3, bx = t2 & 7;
  const float s_x = fmaxf(sc[sx_slot] / 128.0f, EPSF);
  const float s_w = fmaxf(sc[sw_slot] / 127.0f, EPSF);
  gemm_body(A, W, bias, out, s_x*s_w, by*128, bx*128, amax_out, As, Bs, red);
}

// q/k/v f32 (S,B,E) -> qh,kh int8 [BH][S][DH]; vt int8 [BH][DH][S]; vtot[bh][d] = sum_key v
__global__ __launch_bounds__(256) void k_quant_heads(const float* __restrict__ qf,
    const float* __restrict__ kf, const float* __restrict__ vf,
    i8* __restrict__ qh, i8* __restrict__ kh, i8* __restrict__ vt,
    int* __restrict__ vtot, const float* __restrict__ sc){
  const float s_q = fmaxf((sc[7]*0.125f)/128.0f, EPSF);  // scale of q/sqrt(64)
  const float s_k = fmaxf(sc[8]/128.0f, EPSF);
  const float s_v = fmaxf(sc[9]/128.0f, EPSF);
  __shared__ i8 tile[64][68];
  const int bx = blockIdx.x;
  const int st = bx & 15, hh = (bx >> 4) & 15, b = bx >> 8;
  const int t = threadIdx.x;
  const int sl = t >> 2, dc = (t & 3) * 16;
  const size_t row = (size_t)(st*64 + sl)*BATCH + b;
  const size_t ibase = row*EMB + hh*DHEAD + dc;
  const int bh = b*NH + hh;
  float vq[16], vk[16], vv[16];
#pragma unroll
  for (int i = 0; i < 4; i++){
    *(float4*)&vq[i*4] = *(const float4*)&qf[ibase + i*4];
    *(float4*)&vk[i*4] = *(const float4*)&kf[ibase + i*4];
    *(float4*)&vv[i*4] = *(const float4*)&vf[ibase + i*4];
  }
  alignas(16) i8 oq[16], ok[16];
#pragma unroll
  for (int i = 0; i < 16; i++){
    float tq = fminf(fmaxf(rintf((vq[i]*0.125f)/s_q), -128.f), 127.f);
    float tk = fminf(fmaxf(rintf(vk[i]/s_k), -128.f), 127.f);
    float tv = fminf(fmaxf(rintf(vv[i]/s_v), -128.f), 127.f);
    oq[i] = (i8)(int)tq; ok[i] = (i8)(int)tk;
    tile[dc + i][sl] = (i8)(int)tv;
  }
  const size_t qoff = ((size_t)bh*S_LEN + st*64 + sl)*DHEAD + dc;
  *(int4*)&qh[qoff] = *(const int4*)&oq[0];
  *(int4*)&kh[qoff] = *(const int4*)&ok[0];
  __syncthreads();
  const int d = t >> 2, sc4 = (t & 3) * 16;
  int ovi[4];
  int sum = 0;
#pragma unroll
  for (int w4 = 0; w4 < 4; w4++){
    unsigned x = *(const unsigned*)&tile[d][sc4 + w4*4];
    ovi[w4] = (int)x;
#pragma unroll
    for (int bb = 0; bb < 4; bb++) sum += (int)(i8)(x >> (8*bb));
  }
  const size_t voff = ((size_t)bh*DHEAD + d)*S_LEN + st*64 + sc4;
  *(int4*)&vt[voff] = *(const int4*)&ovi[0];
  sum += __shfl_xor(sum, 1);
  sum += __shfl_xor(sum, 2);
  if ((t & 3) == 0) atomicAdd(&vtot[bh*DHEAD + d], sum);
}

// attention pass 1: KVBLK=128, 4 waves / 64 q-rows, grid 1024. SWAPPED int8 QK^T.
// T14 async-stage: K loaded to regs (prefetch next chunk under compute), ds_write at top.
__global__ __launch_bounds__(256) void k_attn1(const i8* __restrict__ qh,
    const i8* __restrict__ kh, float* __restrict__ mrow, float* __restrict__ lrow,
    const float* __restrict__ sc, int* __restrict__ sci){
  __shared__ i8 Ks[128][64];
  __shared__ float red2[4];
  const int orig = blockIdx.x;
  const int tile = (orig & 7) * 128 + (orig >> 3);   // XCD-chunked swizzle
  const int bhead = tile >> 4, q0 = (tile & 15) * 64;
  const int tid = threadIdx.x, w = tid >> 6, lane = tid & 63;
  const int rr = lane & 15, g = lane >> 4;
  const float s_q = fmaxf((sc[7]*0.125f)/128.0f, EPSF);
  const float s_k = fmaxf(sc[8]/128.0f, EPSF);
  const float C1 = s_q * s_k * LOG2E;                // scores scaled to log2 domain
  const i8* qbase = qh + ((size_t)bhead*S_LEN + q0 + w*16)*DHEAD;
  const i8* kbase = kh + (size_t)bhead*S_LEN*DHEAD;
  i32x4 a = *(const i32x4*)&qbase[rr*DHEAD + g*16];  // Q fragment (B operand)
  const int ksel = ((lane & 3) ^ ((lane >> 3) & 3)) << 4;   // lane-only source sel
  const int kr = lane >> 2;                                  // 0..15
  // reg-staged prologue (chunk 0); ds_write dest replicates gload_lds layout
  i8* kdst = (i8*)Ks + w*2048 + lane*16;
  int4 rk0 = *(const int4*)&kbase[(size_t)(w*32 + kr)*DHEAD + ksel];
  int4 rk1 = *(const int4*)&kbase[(size_t)(w*32 + 16 + kr)*DHEAD + ksel];
  float m = -1e30f, l = 0.0f;
  for (int cch = 0; cch < 8; cch++){
    *(int4*)kdst          = rk0;
    *(int4*)(kdst + 1024) = rk1;
    __syncthreads();
    if (cch < 7){
      const int n1 = (cch + 1) * 128;
      rk0 = *(const int4*)&kbase[(size_t)(n1 + w*32 + kr)*DHEAD + ksel];
      rk1 = *(const int4*)&kbase[(size_t)(n1 + w*32 + 16 + kr)*DHEAD + ksel];
    }
    float sv[8][4];
#pragma unroll
    for (int nt = 0; nt < 8; nt++){
      int row = nt*16 + rr;
      i32x4 b = *(const i32x4*)((const i8*)Ks + row*64 + (((g ^ ((row >> 1) & 3))) << 4));
      i32x4 acc = {};
      acc = MFMAI8(b, a, acc);                       // SWAPPED: D[key][q]
#pragma unroll
      for (int r = 0; r < 4; r++) sv[nt][r] = (float)acc[r]*C1;
    }
    float cm = sv[0][0];
#pragma unroll
    for (int nt = 0; nt < 8; nt++)
#pragma unroll
      for (int r = 0; r < 4; r++) cm = fmaxf(cm, sv[nt][r]);
    float mn = fmaxf(m, cm);
    l *= EXP2F(m - mn);                              // 1.0 when max unchanged
    m = mn;
#pragma unroll
    for (int nt = 0; nt < 8; nt++)
#pragma unroll
      for (int r = 0; r < 4; r++) l += EXP2F(sv[nt][r] - m);
    __syncthreads();
  }
  // merge (m,l) across the 4 g-lanes sharing q-row rr
#pragma unroll
  for (int off = 16; off < 64; off <<= 1){
    float mo = __shfl_xor(m, off), lo = __shfl_xor(l, off);
    float mn = fmaxf(m, mo);
    l = l*EXP2F(m - mn) + lo*EXP2F(mo - mn);
    m = mn;
  }
  if (g == 0){
    mrow[(size_t)bhead*S_LEN + q0 + w*16 + rr] = m;  // log2-domain max
    lrow[(size_t)bhead*S_LEN + q0 + w*16 + rr] = l;
  }
  float im = wave_max(1.0f / l);
  if (lane == 0) red2[w] = im;
  __syncthreads();
  if (tid == 0){
    float mm = fmaxf(fmaxf(red2[0], red2[1]), fmaxf(red2[2], red2[3]));
    atomicMax(sci + 13, __float_as_int(mm));
  }
}

// attention pass 2: KVBLK=128. SWAPPED int8 QK^T + int8 PV with -128 offset.
// T14 async-stage for K and V; cvt_pk P-pack (proven R17).
__global__ __launch_bounds__(256) void k_attn2(const i8* __restrict__ qh,
    const i8* __restrict__ kh, const i8* __restrict__ vt,
    const float* __restrict__ mrow, const float* __restrict__ lrow,
    const int* __restrict__ vtot, float* __restrict__ aout,
    const float* __restrict__ sc, const int* __restrict__ sci,
    int* __restrict__ amax_out){
  __shared__ i8 Ks[128][64];
  __shared__ i8 Vs[64][128];
  __shared__ i8 P[4][16][136];
  __shared__ float red[4];
  const int orig = blockIdx.x;
  const int tile = (orig & 7) * 128 + (orig >> 3);   // XCD-chunked swizzle
  const int bhead = tile >> 4, q0 = (tile & 15) * 64;
  const int tid = threadIdx.x, w = tid >> 6, lane = tid & 63;
  const int rr = lane & 15, g = lane >> 4;
  const float s_q = fmaxf((sc[7]*0.125f)/128.0f, EPSF);
  const float s_k = fmaxf(sc[8]/128.0f, EPSF);
  const float C1 = s_q * s_k * LOG2E;
  const float s_v = fmaxf(sc[9]/128.0f, EPSF);
  const float s_a = fmaxf(__int_as_float(sci[13]) / 255.0f, EPSF);
  const float fac = s_a * s_v;
  const i8* qbase = qh + ((size_t)bhead*S_LEN + q0 + w*16)*DHEAD;
  const i8* kbase = kh + (size_t)bhead*S_LEN*DHEAD;
  const i8* vbase = vt + (size_t)bhead*DHEAD*S_LEN;
  i32x4 a = *(const i32x4*)&qbase[rr*DHEAD + g*16];  // Q fragment (B operand)
  float nb;
  {
    size_t qr = (size_t)bhead*S_LEN + q0 + w*16 + rr;
    float inv = 1.0f / (lrow[qr] * s_a);
    nb = log2f(inv) - mrow[qr];
  }
  const int ksel = ((lane & 3) ^ ((lane >> 3) & 3)) << 4;
  const int kr = lane >> 2;                    // 0..15
  const int vsel = (((lane & 7) ^ ((lane >> 3) & 7)) << 4);
  const int vr = lane >> 3;                    // 0..7
  // reg-staged prologue (chunk 0); ds_write dests replicate gload_lds layout
  i8* kdst = (i8*)Ks + w*2048 + lane*16;
  i8* vdst = (i8*)Vs + w*2048 + lane*16;
  int4 rk0 = *(const int4*)&kbase[(size_t)(w*32 + kr)*DHEAD + ksel];
  int4 rk1 = *(const int4*)&kbase[(size_t)(w*32 + 16 + kr)*DHEAD + ksel];
  int4 rv0 = *(const int4*)&vbase[(size_t)(w*16 + vr)*S_LEN + vsel];
  int4 rv1 = *(const int4*)&vbase[(size_t)(w*16 + 8 + vr)*S_LEN + vsel];
  i32x4 cpv[4] = {};
  for (int cch = 0; cch < 8; cch++){
    *(int4*)kdst          = rk0;
    *(int4*)(kdst + 1024) = rk1;
    *(int4*)vdst          = rv0;
    *(int4*)(vdst + 1024) = rv1;
    __syncthreads();
    if (cch < 7){
      const int n1 = (cch + 1) * 128;
      rk0 = *(const int4*)&kbase[(size_t)(n1 + w*32 + kr)*DHEAD + ksel];
      rk1 = *(const int4*)&kbase[(size_t)(n1 + w*32 + 16 + kr)*DHEAD + ksel];
      rv0 = *(const int4*)&vbase[(size_t)(w*16 + vr)*S_LEN + n1 + vsel];
      rv1 = *(const int4*)&vbase[(size_t)(w*16 + 8 + vr)*S_LEN + n1 + vsel];
    }
#pragma unroll
    for (int nt = 0; nt < 8; nt++){
      int row = nt*16 + rr;
      i32x4 b = *(const i32x4*)((const i8*)Ks + row*64 + (((g ^ ((row >> 1) & 3))) << 4));
      i32x4 acc = {};
      acc = MFMAI8(b, a, acc);                       // SWAPPED: D[key][q]
      float er0 = fminf(rintf(EXP2F(fmaf((float)acc[0], C1, nb))), 255.0f);
      float er1 = fminf(rintf(EXP2F(fmaf((float)acc[1], C1, nb))), 255.0f);
      float er2 = fminf(rintf(EXP2F(fmaf((float)acc[2], C1, nb))), 255.0f);
      float er3 = fminf(rintf(EXP2F(fmaf((float)acc[3], C1, nb))), 255.0f);
      unsigned pw;
      asm("v_cvt_pk_u8_f32 %0, %1, 0, 0"  : "=v"(pw) : "v"(er0));
      asm("v_cvt_pk_u8_f32 %0, %1, 1, %0" : "+v"(pw) : "v"(er1));
      asm("v_cvt_pk_u8_f32 %0, %1, 2, %0" : "+v"(pw) : "v"(er2));
      asm("v_cvt_pk_u8_f32 %0, %1, 3, %0" : "+v"(pw) : "v"(er3));
      pw ^= 0x80808080u;                             // -128 per byte
      *(unsigned*)&P[w][rr][nt*16 + g*4] = pw;
    }
    // PV: within-wave P dependency (lgkmcnt orders write->read; no barrier needed)
#pragma unroll
    for (int h = 0; h < 2; h++){
      i32x4 pa;
      {
        const i8* pptr = &P[w][rr][h*64 + g*16];
        pa[0] = *(const int*)(pptr + 0);
        pa[1] = *(const int*)(pptr + 4);
        pa[2] = *(const int*)(pptr + 8);
        pa[3] = *(const int*)(pptr + 12);
      }
#pragma unroll
      for (int f = 0; f < 4; f++){
        int row = f*16 + rr;
        i32x4 bv = *(const i32x4*)((const i8*)Vs + row*128 + (((h*4 + g) ^ (row & 7)) << 4));
        cpv[f] = MFMAI8(pa, bv, cpv[f]);
      }
    }
    __syncthreads();
  }
  const int b = bhead >> 4, hh = bhead & 15;
  float lmax = 0.0f;
#pragma unroll
  for (int f = 0; f < 4; f++){
    int d = f*16 + rr;
    int vcorr = 128 * vtot[bhead*DHEAD + d];
#pragma unroll
    for (int r = 0; r < 4; r++){
      int srow2 = q0 + w*16 + g*4 + r;
      float y = fac * (float)(cpv[f][r] + vcorr);
      aout[(size_t)(srow2*BATCH + b)*EMB + hh*DHEAD + d] = y;
      lmax = fmaxf(lmax, fabsf(y));
    }
  }
  lmax = wave_max(lmax);
  __syncthreads();
  if (lane == 0) red[w] = lmax;
  __syncthreads();
  if (tid == 0){
    float mm = fmaxf(fmaxf(red[0], red[1]), fmaxf(red[2], red[3]));
    atomicMax(amax_out, __float_as_int(mm));
  }
}

extern "C" void kernel_launch(void* const* d_in, const int* in_sizes, int n_in,
                              void* d_out, int out_size, void* d_ws, size_t ws_size,
                              hipStream_t stream){
  const float* query = (const float*)d_in[0];
  const float* key   = (const float*)d_in[1];
  const float* value = (const float*)d_in[2];
  const float* inW   = (const float*)d_in[3];
  const float* inB   = (const float*)d_in[4];
  const float* outW  = (const float*)d_in[5];
  const float* outB  = (const float*)d_in[6];
  float* out = (float*)d_out;

  char* ws = (char*)d_ws;
  float* sc  = (float*)ws;
  int*   sci = (int*)ws;
  int*   vtotI = (int*)(ws + 256);               // 64x64 i32 = 16 KB
  u8* WQQ = (u8*)(ws + 256 + 16384);             // weights int8, 1MB each
  u8* WKQ = WQQ + 1024*1024;
  u8* WVQ = WKQ + 1024*1024;
  u8* WOQ = WVQ + 1024*1024;
  u8* XQ  = WOQ + 1024*1024;                     // acts int8, 4MB each
  u8* XK  = XQ + (size_t)NTOK*1024;
  u8* XV  = XK + (size_t)NTOK*1024;
  float* QF = (float*)(XV + (size_t)NTOK*1024);  // f32, 16MB each
  float* KF = QF + (size_t)NTOK*1024;
  float* VF = KF + (size_t)NTOK*1024;
  i8* VT = (i8*)(VF + (size_t)NTOK*1024);        // int8 V^T, 4MB
  float* MROW = (float*)(VT + (size_t)BHEAD*DHEAD*S_LEN);
  float* LROW = MROW + BHEAD*S_LEN;
  // reuse (lifetimes are disjoint along the serial stream):
  i8* QH  = (i8*)XQ;   i8* KH = (i8*)XK;         // proj-input quants dead after GEMMs
  float* AOUT = QF;                              // q f32 dead after k_quant_heads
  u8* AOQ = XV;                                  // v int8 input dead after gemm3

  AQTable tab;
  tab.d[0] = { query,             XQ,  NTOK*1024/4, 0, 128.f, -128.f };
  tab.d[1] = { key,               XK,  NTOK*1024/4, 1, 128.f, -128.f };
  tab.d[2] = { value,             XV,  NTOK*1024/4, 2, 128.f, -128.f };
  tab.d[3] = { inW,               WQQ, 1024*1024/4, 3, 127.f, -127.f };
  tab.d[4] = { inW + 1024*1024,   WKQ, 1024*1024/4, 4, 127.f, -127.f };
  tab.d[5] = { inW + 2*1024*1024, WVQ, 1024*1024/4, 5, 127.f, -127.f };
  tab.d[6] = { outW,              WOQ, 1024*1024/4, 6, 127.f, -127.f };

  k_zero<<<17, 256, 0, stream>>>(sc, vtotI);
  k_absmax7<<<2048, 256, 0, stream>>>(tab, sci);
  k_quant7<<<2048, 256, 0, stream>>>(tab, sc);
  k_gemm3<<<768, 512, 0, stream>>>((const i8*)XQ, (const i8*)WQQ, inB, QF, sc, sci);
  k_quant_heads<<<1024, 256, 0, stream>>>(QF, KF, VF, QH, KH, VT, vtotI, sc);
  k_attn1<<<1024, 256, 0, stream>>>(QH, KH, MROW, LROW, sc, sci);
  k_attn2<<<1024, 256, 0, stream>>>(QH, KH, VT, MROW, LROW, vtotI, AOUT, sc, sci, sci + 10);
  k_quant<<<1024, 256, 0, stream>>>(AOUT, AOQ, sc, 10);
  k_gemm1<<<256, 512, 0, stream>>>((const i8*)AOQ, (const i8*)WOQ, outB, out, sc, 10, 6, sci + 12);
}